// Round 18
// baseline (1304.543 us; speedup 1.0000x reference)
//
#include <hip/hip_runtime.h>
#include <hip/hip_bf16.h>
#include <math.h>

typedef __bf16 bf16x8 __attribute__((ext_vector_type(8)));
typedef __bf16 bf16x4 __attribute__((ext_vector_type(4)));
typedef float  f32x4  __attribute__((ext_vector_type(4)));

#define MFMA(a,b,c) __builtin_amdgcn_mfma_f32_16x16x32_bf16(a, b, c, 0, 0, 0)
#define LOG2E 1.4426950408889634f

// ---------------- workspace float offsets ----------------
static constexpr size_t OFF_R0    = 0;                       // TWO bf16 qkv buffers (A, B)
static constexpr size_t OFF_GXT   = 12582912;
static constexpr size_t OFF_ACCUM = OFF_GXT;                 // 4,194,304
static constexpr size_t OFF_FINAL = OFF_GXT + 4194304;       // bf16 operand area
static constexpr size_t SOFF      = OFF_GXT + 8388608;
static constexpr size_t OFF_ROWSUM= SOFF;                    // 32768 (mha rowsum; acmp)
static constexpr size_t OFF_ACMP  = OFF_ROWSUM;
static constexpr size_t OFF_COLW  = OFF_ROWSUM + 32768;      // 524288 (mha colw); later raw kvf
static constexpr size_t OFF_BM    = OFF_COLW;                // raw kvf bf16 [64][10240]
static constexpr size_t OFF_ACM   = OFF_COLW + 524288;
static constexpr size_t OFF_XMEAN = OFF_ACM + 4096;
static constexpr size_t OFF_LC    = OFF_XMEAN + 4096;        // 2048
static constexpr size_t OFF_COEF  = OFF_LC + 2048;           // 256
static constexpr size_t OFF_GMIX  = OFF_COEF + 256;          // 16
static constexpr size_t OFF_MW    = OFF_GMIX + 16;           // 4
static constexpr size_t OFF_CONV9 = OFF_MW + 4;              // 5184
static constexpr size_t OFF_CBIAS = OFF_CONV9 + 5184;        // 64
static constexpr size_t OFF_WEFF  = OFF_CBIAS + 64;          // 4096
static constexpr size_t OFF_PPOW  = OFF_WEFF + 4096;         // 1536
static constexpr size_t OFF_LBIAS = OFF_PPOW + 1536;         // 1024
static constexpr size_t OFF_W2    = OFF_LBIAS + 1024;        // 2048
static constexpr size_t OFF_W1CS  = OFF_W2 + 2048;           // 16384 fl = bf16[32][1024]
static constexpr size_t OFF_W1T   = OFF_W1CS + 16384;        // 16384 fl = bf16[1024][32]
static constexpr size_t OFF_HB    = OFF_W1T + 16384;
static constexpr size_t OFF_STATE = OFF_HB;                  // 12288
static constexpr size_t OFF_XP2   = OFF_HB + 16384;          // 65536 [8][16][512]
// bf16 operand area (inside OFF_FINAL)
static constexpr size_t OFF_XB    = OFF_FINAL;
static constexpr size_t OFF_QW    = OFF_FINAL + 2097152;
static constexpr size_t OFF_MW2   = OFF_FINAL + 3276800;
static constexpr size_t OFF_WFB   = OFF_FINAL + 3670016;
static constexpr size_t OFF_WBB   = OFF_FINAL + 3801088;
static constexpr size_t OFF_PWB   = OFF_FINAL + 3932160;

__device__ __forceinline__ float sigm(float x){ return __builtin_amdgcn_rcpf(1.0f + exp2f(-LOG2E*x)); }
__device__ __forceinline__ float tanhx(float x){ return 2.0f*__builtin_amdgcn_rcpf(1.0f + exp2f(-2.0f*LOG2E*x)) - 1.0f; }
__device__ __forceinline__ unsigned pk2(float a, float b){
  union { __bf16 h[2]; unsigned u; } z; z.h[0]=(__bf16)a; z.h[1]=(__bf16)b; return z.u;
}
__device__ __forceinline__ unsigned pk2b(__bf16 a, __bf16 b){
  union { __bf16 h[2]; unsigned u; } z; z.h[0]=a; z.h[1]=b; return z.u;
}
__device__ __forceinline__ void powpair(float t, float p, float& pos, float& neg){
  float a = fabsf(t);
  float v = (a > 0.f) ? exp2f(p * __log2f(a)) : 0.f;
  pos = (t > 0.f) ? v : 0.f;
  neg = (t < 0.f) ? v : 0.f;
}
__device__ __forceinline__ f32x4 fz4(){ return (f32x4){0.f,0.f,0.f,0.f}; }

// ---------------- fp32 -> bf16 copy of one 2048-elt block ----------------
__device__ __forceinline__ void d_cvt_blk(const float* __restrict__ src, __bf16* __restrict__ dst,
                                          int base, int tid){
  int i = (base*256 + tid)*8;
  f32x4 u0 = *(const f32x4*)(src+i), u1 = *(const f32x4*)(src+i+4);
  bf16x8 v;
  #pragma unroll
  for (int j=0;j<4;++j){ v[j]=(__bf16)u0[j]; v[j+4]=(__bf16)u1[j]; }
  *(bf16x8*)(dst+i) = v;
}

// cvt stage A: x + wih_f + wih_b  (2304 blocks)
__global__ void k_cvt_a(const float* __restrict__ x, const float* __restrict__ wih_f,
                        const float* __restrict__ wih_b, float* __restrict__ ws){
  int b = blockIdx.x;
  if (b < 2048)      d_cvt_blk(x,     (__bf16*)(ws+OFF_XB),  b,      threadIdx.x);
  else if (b < 2176) d_cvt_blk(wih_f, (__bf16*)(ws+OFF_WFB), b-2048, threadIdx.x);
  else               d_cvt_blk(wih_b, (__bf16*)(ws+OFF_WBB), b-2176, threadIdx.x);
}

// ---------------- constants / tables ----------------
__global__ void k_const(const float* __restrict__ ge_b1, const float* __restrict__ ge_w2,
                        const float* __restrict__ ge_b2, const float* __restrict__ mode_w,
                        const float* __restrict__ w5, const float* __restrict__ b5,
                        const float* __restrict__ w7, const float* __restrict__ b7,
                        const float* __restrict__ w9, const float* __restrict__ b9,
                        const float* __restrict__ pos_sw, const float* __restrict__ neg_sw,
                        const float* __restrict__ spw,
                        const float* __restrict__ bih_f, const float* __restrict__ bhh_f,
                        const float* __restrict__ bih_b, const float* __restrict__ bhh_b,
                        float* __restrict__ ws){
  int tid = threadIdx.x; // 256
  __shared__ float mw[3];
  __shared__ float tgh[256];
  __shared__ float sbuf[16];
  tgh[tid] = tanhf(ge_b1[tid]);
  if (tid == 0){
    float m0=mode_w[0], m1=mode_w[1], m2=mode_w[2];
    float mx = fmaxf(m0, fmaxf(m1,m2));
    float e0=expf(m0-mx), e1=expf(m1-mx), e2=expf(m2-mx);
    float s = e0+e1+e2;
    mw[0]=e0/s; mw[1]=e1/s; mw[2]=e2/s;
    ws[OFF_MW+0]=mw[0]; ws[OFF_MW+1]=mw[1]; ws[OFF_MW+2]=mw[2];
  }
  __syncthreads();
  if (tid < 16){
    float s = ge_b2[tid];
    for (int i=0;i<256;++i) s += ge_w2[tid*256+i]*tgh[i];
    sbuf[tid] = s;
  }
  __syncthreads();
  if (tid < 8){
    float a = sbuf[2*tid], b = sbuf[2*tid+1];
    float m = fmaxf(a,b);
    float ea = expf(a-m), eb = expf(b-m);
    ws[OFF_GMIX+2*tid]   = ea/(ea+eb);
    ws[OFF_GMIX+2*tid+1] = eb/(ea+eb);
  }
  for (int j=tid;j<512;j+=256){
    ws[OFF_LBIAS+j]     = bih_f[j]+bhh_f[j];
    ws[OFF_LBIAS+512+j] = bih_b[j]+bhh_b[j];
  }
  for (int f=tid; f<5184; f+=256){
    int d=f/81, t=f%81, ky=t/9, kx=t%9, dy=ky-4, dx=kx-4;
    float v = mw[2]*w9[d*81+t];
    if (dy>=-3 && dy<=3 && dx>=-3 && dx<=3) v += mw[1]*w7[d*49 + (dy+3)*7 + (dx+3)];
    if (dy>=-2 && dy<=2 && dx>=-2 && dx<=2) v += mw[0]*w5[d*25 + (dy+2)*5 + (dx+2)];
    ws[OFF_CONV9+f] = v;
  }
  if (tid<64) ws[OFF_CBIAS+tid] = mw[0]*b5[tid]+mw[1]*b7[tid]+mw[2]*b9[tid];
  for (int f=tid; f<2048; f+=256){
    int h=f>>8, k1=(f>>4)&15, k2=f&15;
    int src = ((h*16+k1)*64 + k2)*2;
    ws[OFF_WEFF+2*f]   = pos_sw[src]   + 0.0625f*neg_sw[src];
    ws[OFF_WEFF+2*f+1] = pos_sw[src+1] + 0.0625f*neg_sw[src+1];
  }
  for (int f=tid; f<1536; f+=256) ws[OFF_PPOW+f] = 1.0f + fabsf(spw[f]);
  for (int f=tid; f<1024; f+=256){
    int e=f>>4, k2=f&15; int ph=(e*k2)&63;
    float th = (float)ph * (6.283185307179586f/64.0f);
    ws[OFF_W2+2*f]   = cosf(th);
    ws[OFF_W2+2*f+1] = -sinf(th);
  }
  __bf16* w1cs = (__bf16*)(ws + OFF_W1CS);
  for (int f=tid; f<32768; f+=256){
    int r=f>>10, m=f&1023; int k1=r&15; int ph=(k1*m)&1023;
    float th = (float)ph * (6.283185307179586f/1024.0f);
    w1cs[f] = (__bf16)((r<16)?cosf(th):-sinf(th));
  }
  __bf16* w1t = (__bf16*)(ws + OFF_W1T);
  for (int f=tid; f<32768; f+=256){
    int n=f>>5, r=f&31; int k1=r&15; int ph=(k1*n)&1023;
    float th = (float)ph * (6.283185307179586f/1024.0f);
    w1t[f] = (__bf16)((r<16)?cosf(th):sinf(th));
  }
}

// ================= device component bodies =================

__device__ __forceinline__ void d_gemm(const __bf16* __restrict__ A, const __bf16* __restrict__ W,
                                       const float* __restrict__ bias, __bf16* __restrict__ C,
                                       int NB_N, int N, int K, int o, int nwg, int tid, char* smraw){
  __bf16 (*As)[40] = (__bf16(*)[40])smraw;
  __bf16 (*Ws)[40] = (__bf16(*)[40])(smraw + 10240);
  int cpx = nwg >> 3;
  int wg = (o & 7)*cpx + (o >> 3);
  int n0 = (wg % NB_N) * 128, m0 = (wg / NB_N) * 128;
  int l = tid & 63, wid = tid >> 6, lr = l & 15, lg = l >> 4;
  int wr = wid >> 1, wc = wid & 1;
  f32x4 acc[4][4];
  #pragma unroll
  for (int i=0;i<4;++i){ acc[i][0]=fz4(); acc[i][1]=fz4(); acc[i][2]=fz4(); acc[i][3]=fz4(); }
  int srow = tid >> 1, sk = (tid & 1) * 16;
  const __bf16* Ap = A + (size_t)(m0 + srow) * K + sk;
  const __bf16* Wp = W + (size_t)(n0 + srow) * K + sk;
  for (int k0 = 0; k0 < K; k0 += 32){
    bf16x8 a0 = *(const bf16x8*)(Ap), a1 = *(const bf16x8*)(Ap+8);
    bf16x8 w0 = *(const bf16x8*)(Wp), w1 = *(const bf16x8*)(Wp+8);
    Ap += 32; Wp += 32;
    __syncthreads();
    *(bf16x8*)&As[srow][sk]   = a0;  *(bf16x8*)&As[srow][sk+8] = a1;
    *(bf16x8*)&Ws[srow][sk]   = w0;  *(bf16x8*)&Ws[srow][sk+8] = w1;
    __syncthreads();
    bf16x8 aF[4], bF[4];
    #pragma unroll
    for (int mf=0;mf<4;++mf) aF[mf] = *(const bf16x8*)&As[wr*64+mf*16+lr][lg*8];
    #pragma unroll
    for (int nf=0;nf<4;++nf) bF[nf] = *(const bf16x8*)&Ws[wc*64+nf*16+lr][lg*8];
    #pragma unroll
    for (int mf=0;mf<4;++mf)
      #pragma unroll
      for (int nf=0;nf<4;++nf) acc[mf][nf] = MFMA(aF[mf], bF[nf], acc[mf][nf]);
  }
  #pragma unroll
  for (int mf=0;mf<4;++mf)
    #pragma unroll
    for (int nf=0;nf<4;++nf){
      int row = m0 + wr*64 + mf*16 + lg*4;
      int col = n0 + wc*64 + nf*16 + lr;
      float bv = bias ? bias[col] : 0.f;
      #pragma unroll
      for (int r=0;r<4;++r) C[(size_t)(row+r)*N + col] = (__bf16)(acc[mf][nf][r] + bv);
    }
}

// ---- LSTM scan half (512 steps). gates bf16 [b][t][1024]. ----
template<int PHASE>
__device__ __forceinline__ void d_lstm(const float* __restrict__ whh_f, const float* __restrict__ whh_b,
                                       const __bf16* __restrict__ gates, float* __restrict__ lc,
                                       float* __restrict__ state, int bid, int tid, char* smraw){
  __builtin_amdgcn_s_setprio(1);
  int dir = bid >> 3, b = bid & 7;
  const float* __restrict__ whh = dir ? whh_b : whh_f;
  const __bf16* gx = gates + (size_t)b*1048576;
  int w=tid>>6, l=tid&63, lr=l&15, lg=l>>4;
  bf16x8 wf[4][2][4];
  #pragma unroll
  for (int q=0;q<4;++q)
    #pragma unroll
    for (int t=0;t<2;++t)
      #pragma unroll
      for (int kc=0;kc<4;++kc){
        const float* p = whh + (size_t)(q*128 + w*32 + t*16 + lr)*128 + kc*32 + lg*8;
        bf16x8 v;
        #pragma unroll
        for (int j=0;j<8;++j) v[j]=(__bf16)p[j];
        wf[q][t][kc]=v;
      }
  __bf16 (*hbuf)[132] = (__bf16(*)[132])smraw;
  int tsel = l&1, rsel = (l>>1)&3;
  int hrow = w*32 + tsel*16 + lg*4 + rsel;
  float* st = state + bid*768 + tid*3;
  float cs, hs;
  if (PHASE==0){
    for (int i=tid; i<264; i+=256) ((__bf16*)hbuf)[i] = (__bf16)0.0f;
    cs=0.f; hs=0.f;
  } else {
    cs = st[0]; hs = st[1];
    hbuf[0][hrow] = (__bf16)st[2];
  }
  long t0 = (PHASE==0) ? (dir?1023:0) : (dir?511:512);
  long tstride = dir ? -1024 : 1024;
  long toff = t0*1024 + dir*512 + hrow;
  float g0[4], g1[4], g2[4], g3[4];
  #pragma unroll
  for (int q=0;q<4;++q) g0[q] = (float)gx[toff + q*128];
  toff += tstride;
  #pragma unroll
  for (int q=0;q<4;++q) g1[q] = (float)gx[toff + q*128];
  toff += tstride;
  #pragma unroll
  for (int q=0;q<4;++q) g2[q] = (float)gx[toff + q*128];
  toff += tstride;
  #pragma unroll
  for (int q=0;q<4;++q) g3[q] = (float)gx[toff + q*128];
  toff += tstride;
  __syncthreads();

#define LSTM_STEP(RB, WB, G) { \
    float gq[4]; \
    _Pragma("unroll") for (int q=0;q<4;++q) gq[q]=G[q]; \
    _Pragma("unroll") for (int q=0;q<4;++q) G[q] = (float)gx[toff + q*128]; \
    toff += tstride; \
    if (toff < 0) toff = 0; \
    if (toff > 1048000) toff = 1048000; \
    bf16x8 hf[4]; \
    _Pragma("unroll") for (int kc=0;kc<4;++kc) hf[kc] = *(const bf16x8*)&hbuf[RB][kc*32 + lg*8]; \
    f32x4 acc[4][2]; \
    _Pragma("unroll") for (int q=0;q<4;++q){ acc[q][0]=fz4(); acc[q][1]=fz4(); } \
    _Pragma("unroll") for (int kc=0;kc<4;++kc) \
      _Pragma("unroll") for (int q=0;q<4;++q){ \
        acc[q][0] = MFMA(wf[q][0][kc], hf[kc], acc[q][0]); \
        acc[q][1] = MFMA(wf[q][1][kc], hf[kc], acc[q][1]); } \
    float gv[4]; \
    _Pragma("unroll") for (int q=0;q<4;++q){ \
      f32x4 v0 = acc[q][0], v1 = acc[q][1]; \
      float a01 = (rsel&1) ? v0[1] : v0[0]; \
      float a23 = (rsel&1) ? v0[3] : v0[2]; \
      float av  = (rsel&2) ? a23 : a01; \
      float b01 = (rsel&1) ? v1[1] : v1[0]; \
      float b23 = (rsel&1) ? v1[3] : v1[2]; \
      float bv  = (rsel&2) ? b23 : b01; \
      gv[q] = (tsel ? bv : av) + gq[q]; } \
    float ii=sigm(gv[0]), ff=sigm(gv[1]), gg=tanhx(gv[2]), oo=sigm(gv[3]); \
    cs = ff*cs + ii*gg; \
    float hv = oo*tanhx(cs); \
    hs += hv; \
    if (!(l&8)) hbuf[WB][hrow] = (__bf16)hv; \
    asm volatile("s_waitcnt lgkmcnt(0)" ::: "memory"); \
    __builtin_amdgcn_sched_barrier(0); \
    __builtin_amdgcn_s_barrier(); \
    __builtin_amdgcn_sched_barrier(0); }

  for (int it=0; it<128; ++it){
    LSTM_STEP(0, 1, g0)
    LSTM_STEP(1, 0, g1)
    LSTM_STEP(0, 1, g2)
    LSTM_STEP(1, 0, g3)
  }
#undef LSTM_STEP
  if (PHASE==0){
    st[0]=cs; st[1]=hs; st[2]=(float)hbuf[0][hrow];
  } else {
    if (!(l&8)) lc[b*256 + dir*128 + hrow] = hs*(1.f/1024.f);
  }
  __builtin_amdgcn_s_setprio(0);
}

__device__ __forceinline__ void d_xmean(const float* __restrict__ x, float* __restrict__ xpart,
                                        int f, int tid){
  int sl = f & 15, b = f >> 4;
  #pragma unroll
  for (int cc=0; cc<2; ++cc){
    int c = tid + cc*256;
    float s=0.f;
    for (int n=sl*64; n<sl*64+64; ++n) s += x[((size_t)(b*1024+n))*512 + c];
    xpart[((size_t)(b*16+sl))*512 + c] = s;
  }
}

// ---- MHA sweep (MODE 1: rowsum, MODE 2: colw) ----
template<int MODE>
__device__ __forceinline__ void d_mha(const __bf16* __restrict__ qkv, float* __restrict__ rowsum,
                                      float* __restrict__ colw, int f, int tid, char* smraw){
  int rb = f & 3, h2 = (f>>2) & 3, b = f >> 4;
  __bf16 (*Qs)[136] = (__bf16(*)[136])smraw;
  __bf16 (*Ks)[136] = (__bf16(*)[136])(smraw + 69632);
  int l=tid&63, w=tid>>6, lr=l&15, lg=l>>4;
  {
    const float qs = LOG2E / sqrtf(128.0f);
    int row = tid;
    const __bf16* p = qkv + ((size_t)(b*1024 + rb*256 + row))*1536 + h2*128;
    #pragma unroll
    for (int cc=0; cc<128; cc+=8){
      bf16x8 u = *(const bf16x8*)(p+cc);
      bf16x8 v;
      #pragma unroll
      for (int j=0;j<8;++j) v[j]=(__bf16)((float)u[j]*qs);
      *(bf16x8*)&Qs[row][cc] = v;
    }
  }
  float rs[4][4];
  if (MODE==1){
    #pragma unroll
    for (int mf=0;mf<4;++mf){ rs[mf][0]=0.f; rs[mf][1]=0.f; rs[mf][2]=0.f; rs[mf][3]=0.f; }
  } else {
    #pragma unroll
    for (int mf=0;mf<4;++mf)
      #pragma unroll
      for (int r=0;r<4;++r)
        rs[mf][r] = 1.0f / rowsum[((size_t)(b*4+h2))*1024 + rb*256 + w*64 + mf*16 + lg*4 + r];
  }
  for (int mc=0; mc<8; ++mc){
    __syncthreads();
    {
      int row = tid>>1, co = (tid&1)*64;
      const __bf16* p = qkv + ((size_t)(b*1024 + mc*128 + row))*1536 + 512 + h2*128 + co;
      #pragma unroll
      for (int cc=0; cc<64; cc+=8)
        *(bf16x8*)&Ks[row][co+cc] = *(const bf16x8*)(p+cc);
    }
    __syncthreads();
    f32x4 acc[4][8];
    #pragma unroll
    for (int mf=0;mf<4;++mf)
      #pragma unroll
      for (int nf=0;nf<8;++nf) acc[mf][nf]=fz4();
    #pragma unroll
    for (int ks=0;ks<4;++ks){
      bf16x8 aF[4], bFv[8];
      #pragma unroll
      for (int mf=0;mf<4;++mf) aF[mf] = *(const bf16x8*)&Qs[w*64+mf*16+lr][ks*32+lg*8];
      #pragma unroll
      for (int nf=0;nf<8;++nf) bFv[nf] = *(const bf16x8*)&Ks[nf*16+lr][ks*32+lg*8];
      #pragma unroll
      for (int mf=0;mf<4;++mf)
        #pragma unroll
        for (int nf=0;nf<8;++nf) acc[mf][nf] = MFMA(aF[mf], bFv[nf], acc[mf][nf]);
    }
    if (MODE==1){
      #pragma unroll
      for (int mf=0;mf<4;++mf)
        #pragma unroll
        for (int nf=0;nf<8;++nf)
          #pragma unroll
          for (int r=0;r<4;++r) rs[mf][r] += exp2f(acc[mf][nf][r]);
    } else {
      #pragma unroll
      for (int nf=0;nf<8;++nf){
        float cv = 0.f;
        #pragma unroll
        for (int mf=0;mf<4;++mf)
          #pragma unroll
          for (int r=0;r<4;++r) cv += exp2f(acc[mf][nf][r])*rs[mf][r];
        cv += __shfl_xor(cv,16);
        cv += __shfl_xor(cv,32);
        if (lg==0)
          colw[(((size_t)(rb*4+w)*8 + b)*4 + h2)*1024 + mc*128 + nf*16 + lr] = cv;
      }
    }
  }
  if (MODE==1){
    #pragma unroll
    for (int mf=0;mf<4;++mf)
      #pragma unroll
      for (int r=0;r<4;++r){
        float v = rs[mf][r];
        v += __shfl_xor(v,1); v += __shfl_xor(v,2); v += __shfl_xor(v,4); v += __shfl_xor(v,8);
        if (lr==0) rowsum[((size_t)(b*4+h2))*1024 + rb*256 + w*64 + mf*16 + lg*4 + r] = v;
      }
  }
}

// ---- spectral fused (in-place q/k) ----
__device__ __forceinline__ void d_spec(__bf16* __restrict__ qkv, const float* __restrict__ ws,
                                       int f, int tid, char* smraw){
  int qk = f & 1, h = (f>>1) & 7, b = f >> 4;
  int colbase = qk*512 + h*64;
  int l=tid&63, w=tid>>6, lr=l&15, lg=l>>4;
  __bf16 (*tT)[520] = (__bf16(*)[520])smraw;                 // 66560 B
  float (*M1)[64]   = (float(*)[64])(smraw + 66560);          // 8192 B
  float (*G2)[2]    = (float(*)[2])(smraw + 66560 + 8192);    // 2048 B
  __bf16* hbl       = (__bf16*)(smraw + 66560 + 8192 + 2048); // 4096 B
  const __bf16* w1cs = (const __bf16*)(ws + OFF_W1CS);
  f32x4 acc1[2]; acc1[0]=fz4(); acc1[1]=fz4();
  for (int c0=0; c0<2; ++c0){
    __syncthreads();
    {
      int p = tid;
      int m0 = c0*512 + 2*p;
      const __bf16* r0 = qkv + ((size_t)(b*1024 + m0))*1536 + colbase;
      const __bf16* r1 = r0 + 1536;
      #pragma unroll
      for (int e=0;e<64;e+=8){
        bf16x8 u0 = *(const bf16x8*)(r0+e);
        bf16x8 u1 = *(const bf16x8*)(r1+e);
        #pragma unroll
        for (int j=0;j<8;++j) *(unsigned*)&tT[e+j][2*p] = pk2b(u0[j], u1[j]);
      }
    }
    __syncthreads();
    for (int ks=0; ks<16; ++ks){
      bf16x8 bfv = *(const bf16x8*)&tT[w*16+lr][ks*32+lg*8];
      #pragma unroll
      for (int mf=0;mf<2;++mf){
        bf16x8 af = *(const bf16x8*)(w1cs + (size_t)(mf*16+lr)*1024 + c0*512 + ks*32 + lg*8);
        acc1[mf] = MFMA(af, bfv, acc1[mf]);
      }
    }
  }
  #pragma unroll
  for (int mf=0;mf<2;++mf)
    #pragma unroll
    for (int r=0;r<4;++r) M1[mf*16 + lg*4 + r][w*16 + lr] = acc1[mf][r];
  __syncthreads();
  {
    int k1 = tid>>4, k2 = tid&15;
    float tfr=0.f, tfi=0.f;
    const float* w2 = ws + OFF_W2;
    for (int e=0;e<64;++e){
      float mr = M1[k1][e], mi = M1[16+k1][e];
      float cr = w2[(e*16+k2)*2], ci = w2[(e*16+k2)*2+1];
      tfr += mr*cr - mi*ci;
      tfi += mr*ci + mi*cr;
    }
    float wr = ws[OFF_WEFF + ((size_t)h*256 + k1*16 + k2)*2];
    float wi = ws[OFF_WEFF + ((size_t)h*256 + k1*16 + k2)*2 + 1];
    G2[tid][0] = tfr*wr - tfi*wi;
    G2[tid][1] = tfr*wi + tfi*wr;
  }
  __syncthreads();
  {
    const float* w2 = ws + OFF_W2;
    for (int f2=tid; f2<1024; f2+=256){
      int k1 = f2>>6, d = f2&63;
      float hr=0.f, hi=0.f;
      #pragma unroll
      for (int k2=0;k2<16;++k2){
        float gr=G2[k1*16+k2][0], gi=G2[k1*16+k2][1];
        float sc = k2 ? 2.f : 1.f;
        float cr = sc*w2[(d*16+k2)*2];
        float ci = -sc*w2[(d*16+k2)*2+1];
        hr += gr*cr - gi*ci;
        hi += gr*ci + gi*cr;
      }
      const float inv = 1.0f/65536.0f;
      hbl[d*32 + k1]      = (__bf16)(hr*inv);
      hbl[d*32 + 16 + k1] = (__bf16)(-hi*inv);
    }
  }
  __syncthreads();
  const __bf16* w1t = (const __bf16*)(ws + OFF_W1T);
  bf16x8 bF[4];
  #pragma unroll
  for (int nf=0;nf<4;++nf) bF[nf] = *(const bf16x8*)&hbl[(nf*16+lr)*32 + lg*8];
  for (int pass=0; pass<4; ++pass){
    int rowbase = w*256 + pass*64;
    f32x4 acc[4][4];
    #pragma unroll
    for (int mf=0;mf<4;++mf){ acc[mf][0]=fz4(); acc[mf][1]=fz4(); acc[mf][2]=fz4(); acc[mf][3]=fz4(); }
    #pragma unroll
    for (int mf=0;mf<4;++mf){
      bf16x8 aF = *(const bf16x8*)(w1t + (size_t)(rowbase+mf*16+lr)*32 + lg*8);
      #pragma unroll
      for (int nf=0;nf<4;++nf) acc[mf][nf] = MFMA(aF, bF[nf], acc[mf][nf]);
    }
    #pragma unroll
    for (int mf=0;mf<4;++mf)
      #pragma unroll
      for (int nf=0;nf<4;++nf)
        #pragma unroll
        for (int r=0;r<4;++r){
          int n = rowbase + mf*16 + lg*4 + r;
          int d = nf*16 + lr;
          qkv[((size_t)(b*1024+n))*1536 + colbase + d] = (__bf16)acc[mf][nf][r];
        }
  }
}

// ---- conv (init: write, else add) ----
__device__ __forceinline__ void d_conv(const __bf16* __restrict__ qkv, const float* __restrict__ ws,
                                       float* __restrict__ accum, int f, int tid, char* smraw, bool init){
  int sl = f & 3, h = (f>>2)&7, b = f>>5;
  float (*vs)[16] = (float(*)[16])smraw;                 // 65536 B
  float (*wc)[81] = (float(*)[81])(smraw + 65536);       // 5184 B
  float* cb       = (float*)(smraw + 65536 + 5184);      // 64 B
  #pragma unroll
  for (int it=0; it<8; ++it){
    int flat = tid + 256*it;
    int pix = flat>>1, cg = (flat&1)*8;
    bf16x8 u = *(const bf16x8*)(qkv + ((size_t)(b*1024+pix))*1536 + 1024 + h*64 + sl*16 + cg);
    #pragma unroll
    for (int j=0;j<8;++j) vs[pix][cg+j] = (float)u[j];
  }
  for (int f2=tid; f2<16*81; f2+=256) wc[f2/81][f2%81] = ws[OFF_CONV9 + (size_t)(sl*16 + f2/81)*81 + (f2%81)];
  if (tid<16) cb[tid] = ws[OFF_CBIAS + sl*16 + tid];
  __syncthreads();
  #pragma unroll
  for (int cc=0; cc<2; ++cc){
    int col = tid + 256*cc;
    int c = col & 15, x = col >> 4;
    float a[32];
    #pragma unroll
    for (int y=0;y<32;++y) a[y]=0.f;
    #pragma unroll
    for (int dx=-4; dx<=4; ++dx){
      int xx = x+dx;
      bool xv = (xx>=0)&&(xx<32);
      float colv[40];
      #pragma unroll
      for (int i=0;i<40;++i){
        int yy = i-4;
        colv[i] = (xv && yy>=0 && yy<32) ? vs[yy*32+xx][c] : 0.f;
      }
      #pragma unroll
      for (int dy=0; dy<9; ++dy){
        float wv = wc[c][dy*9 + dx+4];
        #pragma unroll
        for (int y=0;y<32;++y) a[y] += wv*colv[y+dy];
      }
    }
    float bias = cb[c];
    #pragma unroll
    for (int y=0;y<32;++y){
      size_t oi = ((size_t)((b*8+h)*1024) + y*32 + x)*64 + sl*16 + c;
      if (init) accum[oi] = a[y] + bias;
      else      accum[oi] += a[y] + bias;
    }
  }
}

// ---- polarity KV reduction -> RAW kvf bf16 (no coeffs dependency). f = h + 8*b ----
__device__ __forceinline__ void d_polar_kv_raw(const __bf16* __restrict__ qkv, float* __restrict__ ws,
                                               int s, int f, int tid, char* smraw){
  int h = f & 7, b = f >> 3;
  int l=tid&63, w=tid>>6, lr=l&15, lg=l>>4;
  float* plds = (float*)smraw;
  __bf16* kpT = (__bf16*)smraw;
  __bf16* knT = (__bf16*)(smraw + 17408);
  __bf16* vT  = (__bf16*)(smraw + 34816);
  float* pvs  = (float*)(smraw + 56576);
  if (tid<64) pvs[tid] = ws[OFF_PPOW + ((size_t)s*8+h)*64 + tid];
  for (int i=tid; i<16*136; i+=256) vT[64*136 + i] = (__bf16)((i<136)?1.0f:0.0f);
  f32x4 acc[4][5];
  #pragma unroll
  for (int mf=0;mf<4;++mf)
    #pragma unroll
    for (int nf=0;nf<5;++nf) acc[mf][nf]=fz4();
  for (int mc=0;mc<8;++mc){
    __syncthreads();
    #pragma unroll
    for (int it=0; it<16; ++it){
      int flat = tid + 256*it;
      int d = flat & 63, np = flat >> 6;
      int n = mc*128 + 2*np;
      const __bf16* kr = qkv + ((size_t)(b*1024+n))*1536 + 512 + h*64 + d;
      const __bf16* vr = qkv + ((size_t)(b*1024+n))*1536 + 1024 + h*64 + d;
      float p = pvs[d];
      float k0=(float)kr[0], k1=(float)kr[1536];
      float kp0,kn0,kp1,kn1;
      powpair(k0,p,kp0,kn0); powpair(k1,p,kp1,kn1);
      *(unsigned*)&kpT[d*136 + 2*np] = pk2(kp0,kp1);
      *(unsigned*)&knT[d*136 + 2*np] = pk2(kn0,kn1);
      *(unsigned*)&vT [d*136 + 2*np] = pk2b(vr[0], vr[1536]);
    }
    __syncthreads();
    const __bf16* A = (w&2)?knT:kpT;
    int kh = (w&1)*64;
    #pragma unroll
    for (int ks=0;ks<2;++ks){
      bf16x8 aF[4];
      #pragma unroll
      for (int mf=0;mf<4;++mf) aF[mf] = *(const bf16x8*)&A[(mf*16+lr)*136 + kh + ks*32 + lg*8];
      #pragma unroll
      for (int nf=0;nf<5;++nf){
        bf16x8 bFv = *(const bf16x8*)&vT[(nf*16+lr)*136 + kh + ks*32 + lg*8];
        #pragma unroll
        for (int mf=0;mf<4;++mf) acc[mf][nf] = MFMA(aF[mf], bFv, acc[mf][nf]);
      }
    }
  }
  __syncthreads();
  float* kvf = plds;  // [2][64][80] fp32 overlay (40960 B)
  if ((w&1)==0){
    int mat = w>>1;
    #pragma unroll
    for (int mf=0;mf<4;++mf)
      #pragma unroll
      for (int nf=0;nf<5;++nf)
        #pragma unroll
        for (int r=0;r<4;++r)
          kvf[((size_t)mat*64 + mf*16+lg*4+r)*80 + nf*16+lr] = acc[mf][nf][r];
  }
  __syncthreads();
  if (w&1){
    int mat = w>>1;
    #pragma unroll
    for (int mf=0;mf<4;++mf)
      #pragma unroll
      for (int nf=0;nf<5;++nf)
        #pragma unroll
        for (int r=0;r<4;++r)
          kvf[((size_t)mat*64 + mf*16+lg*4+r)*80 + nf*16+lr] += acc[mf][nf][r];
  }
  __syncthreads();
  __bf16* kvo = (__bf16*)(ws + OFF_BM) + (size_t)(b*8+h)*10240;
  for (int f2=tid; f2<10240; f2+=256) kvo[f2] = (__bf16)kvf[f2];
}

// ---- polarity apply: Bm built from raw kvf + coeffs. f = pass8 + 8*(h + 8*b) ----
__device__ __forceinline__ void d_polar_ap(const __bf16* __restrict__ qkv, const float* __restrict__ ws,
                                           float* __restrict__ accum, int s, int f, int tid, char* smraw){
  int pass8 = f & 7, h = (f>>3)&7, b = f>>6;
  int l=tid&63, w=tid>>6, lr=l&15, lg=l>>4;
  __bf16* At  = (__bf16*)smraw;                 // 34816 B
  __bf16* BmL = (__bf16*)(smraw + 34816);       // 21760 B
  float* zb   = (float*)(smraw + 56576);        // 512 B
  float* pvs  = (float*)(smraw + 57088);        // 256 B
  float* scal = (float*)(smraw + 57344);        // 32 B
  if (tid<64) pvs[tid] = ws[OFF_PPOW + ((size_t)s*8+h)*64 + tid];
  if (tid<4)  scal[tid] = ws[OFF_COEF + b*32 + h*4 + tid];
  if (tid==4) scal[4] = ws[OFF_GMIX + 2*h];
  if (tid==5) scal[5] = ws[OFF_GMIX + 2*h+1];
  __syncthreads();
  {
    const __bf16* kvr = (const __bf16*)(ws + OFF_BM) + (size_t)(b*8+h)*10240;
    float c0=scal[0], c1=scal[1], c2=scal[2], c3=scal[3], g0=scal[4], g1=scal[5];
    for (int u=tid; u<80*128; u+=256){
      int e=u>>7, kk=u&127;
      float v;
      if (e<64){
        if (kk<64) v = g0*c0*(float)kvr[kk*80+e] + g1*c2*(float)kvr[5120 + kk*80+e];
        else { int k2=kk-64; v = g0*c1*(float)kvr[5120 + k2*80+e] + g1*c3*(float)kvr[k2*80+e]; }
      } else if (e==64){
        v = (kk<64) ? (float)kvr[kk*80+64] : (float)kvr[5120 + (kk-64)*80+64];
      } else v = 0.f;
      BmL[e*136+kk] = (__bf16)v;
    }
  }
  #pragma unroll
  for (int it=0; it<8; ++it){
    int flat = tid + 256*it;
    int row = flat>>4, dg = flat&15;
    int n = pass8*128 + row;
    const __bf16* qr = qkv + ((size_t)(b*1024+n))*1536 + h*64 + dg*4;
    bf16x4 u = *(const bf16x4*)qr;
    float qp[4], qn[4];
    #pragma unroll
    for (int j=0;j<4;++j) powpair((float)u[j], pvs[dg*4+j], qp[j], qn[j]);
    *(unsigned*)&At[(row*136) + dg*4]        = pk2(qp[0],qp[1]);
    *(unsigned*)&At[(row*136) + dg*4+2]      = pk2(qp[2],qp[3]);
    *(unsigned*)&At[(row*136) + 64 + dg*4]   = pk2(qn[0],qn[1]);
    *(unsigned*)&At[(row*136) + 64 + dg*4+2] = pk2(qn[2],qn[3]);
  }
  __syncthreads();
  f32x4 a2[2][5];
  #pragma unroll
  for (int mf=0;mf<2;++mf)
    #pragma unroll
    for (int nf=0;nf<5;++nf) a2[mf][nf]=fz4();
  #pragma unroll
  for (int ks=0;ks<4;++ks){
    bf16x8 aF[2];
    #pragma unroll
    for (int mf=0;mf<2;++mf) aF[mf] = *(const bf16x8*)&At[(w*32+mf*16+lr)*136 + ks*32 + lg*8];
    #pragma unroll
    for (int nf=0;nf<5;++nf){
      bf16x8 bFv = *(const bf16x8*)&BmL[(nf*16+lr)*136 + ks*32 + lg*8];
      #pragma unroll
      for (int mf=0;mf<2;++mf) a2[mf][nf] = MFMA(aF[mf], bFv, a2[mf][nf]);
    }
  }
  if (lr==0){
    #pragma unroll
    for (int mf=0;mf<2;++mf)
      #pragma unroll
      for (int r=0;r<4;++r) zb[w*32 + mf*16 + lg*4 + r] = a2[mf][4][r] + 1e-6f;
  }
  __syncthreads();
  #pragma unroll
  for (int mf=0;mf<2;++mf){
    float rz[4];
    #pragma unroll
    for (int r=0;r<4;++r) rz[r] = 1.0f / zb[w*32 + mf*16 + lg*4 + r];
    #pragma unroll
    for (int nf=0;nf<4;++nf)
      #pragma unroll
      for (int r=0;r<4;++r){
        int n = pass8*128 + w*32 + mf*16 + lg*4 + r;
        int e = nf*16 + lr;
        size_t oi = ((size_t)((b*8+h)*1024) + n)*64 + e;
        accum[oi] += a2[mf][nf][r]*rz[r];
      }
  }
}

// ---- coeffs (f = b) ----
__device__ __forceinline__ void d_coeffs(float* __restrict__ ws,
                        const float* __restrict__ mow, const float* __restrict__ mob,
                        const float* __restrict__ ca_w1, const float* __restrict__ ca_b1,
                        const float* __restrict__ ca_w2, const float* __restrict__ ca_b2,
                        int f, int tid, char* smraw){
  int b = f;
  float* av   = (float*)smraw;          // 512
  float* comb = av + 512;               // 512
  float* hid  = comb + 512;             // 256
  for (int i=tid;i<512;i+=256){
    float s = 0.f;
    #pragma unroll
    for (int ms=0; ms<8; ++ms) s += ws[OFF_ACMP + ((size_t)(ms*8+b))*512 + i];
    av[i] = s*(1.f/1024.f);
  }
  __syncthreads();
  for (int c=tid;c<512;c+=256){
    float s = mob[c];
    for (int k=0;k<512;++k) s += mow[(size_t)c*512+k]*av[k];
    float xm = 0.f;
    #pragma unroll
    for (int sl=0; sl<16; ++sl) xm += ws[OFF_XP2 + ((size_t)(b*16+sl))*512 + c];
    comb[c] = s + xm*(1.f/1024.f) + ((c<256) ? ws[OFF_LC + b*256 + c] : 0.f);
  }
  __syncthreads();
  for (int j=tid;j<256;j+=256){
    float s = ca_b1[j];
    for (int k=0;k<512;++k) s += ca_w1[(size_t)j*512+k]*comb[k];
    hid[j] = fmaxf(s,0.f);
  }
  __syncthreads();
  if (tid<32){
    float s = ca_b2[tid];
    for (int k=0;k<256;++k) s += ca_w2[tid*256+k]*hid[k];
    ws[OFF_COEF + b*32 + tid] = 1.f/(1.f+expf(-s));
  }
}

// ---- cvt remainder (f indexes qkv_w / mha_in_w / proj_w) ----
__device__ __forceinline__ void d_cvt_rest(const float* __restrict__ qkv_w, const float* __restrict__ mha_in_w,
                                           const float* __restrict__ proj_w, float* __restrict__ ws,
                                           int f, int tid){
  if (f < 1152)      d_cvt_blk(qkv_w,    (__bf16*)(ws+OFF_QW),  f,      tid);
  else if (f < 1536) d_cvt_blk(mha_in_w, (__bf16*)(ws+OFF_MW2), f-1152, tid);
  else               d_cvt_blk(proj_w,   (__bf16*)(ws+OFF_PWB), f-1536, tid);
}

// ================= kernels =================

// MEGA0: gates GEMM(512) | cvt_rest(1664)
__global__ __launch_bounds__(256,2) void k_mega0(const __bf16* __restrict__ xb, const __bf16* __restrict__ wfb,
                                                 const float* __restrict__ lbias, __bf16* __restrict__ gatesb,
                                                 const float* __restrict__ qkv_w, const float* __restrict__ mha_in_w,
                                                 const float* __restrict__ proj_w, float* __restrict__ ws){
  __shared__ __align__(16) char sm[20480];
  int bid = blockIdx.x, tid = threadIdx.x;
  if (bid < 512) d_gemm(xb, wfb, lbias, gatesb, 8, 1024, 512, bid, 512, tid, sm);
  else           d_cvt_rest(qkv_w, mha_in_w, proj_w, ws, bid-512, tid);
}

// MEGA1: scan_p1(16) | mha GEMM->A(768) | qkv0 GEMM->B(768) | xmean(128)
__global__ __launch_bounds__(256,1) void k_mega1(const float* __restrict__ whh_f, const float* __restrict__ whh_b,
                                                 const __bf16* __restrict__ gates, float* __restrict__ ws,
                                                 const float* __restrict__ x,
                                                 const __bf16* __restrict__ xb, const __bf16* __restrict__ mwb,
                                                 const __bf16* __restrict__ qwb,
                                                 const float* __restrict__ mha_in_b,
                                                 __bf16* __restrict__ qkvA, __bf16* __restrict__ qkvB){
  __shared__ __align__(16) char sm[20480];
  int bid = blockIdx.x, tid = threadIdx.x;
  if (bid < 16)         d_lstm<0>(whh_f, whh_b, gates, ws+OFF_LC, ws+OFF_STATE, bid, tid, sm);
  else if (bid < 784)   d_gemm(xb, mwb, mha_in_b, qkvA, 12, 1536, 512, bid-16, 768, tid, sm);
  else if (bid < 1552)  d_gemm(xb, qwb, nullptr,   qkvB, 12, 1536, 512, bid-784, 768, tid, sm);
  else                  d_xmean(x, ws+OFF_XP2, bid-1552, tid);
}

// MEGA2: scan_p2(16) | spec0(128) | mha<1>(128) | conv0-init(256)
__global__ __launch_bounds__(256,1) void k_mega2(const float* __restrict__ whh_f, const float* __restrict__ whh_b,
                                                 const __bf16* __restrict__ gates, float* __restrict__ ws,
                                                 const __bf16* __restrict__ qkvA, __bf16* __restrict__ qkvB,
                                                 float* __restrict__ accum){
  __shared__ __align__(16) char sm[104448];
  int bid = blockIdx.x, tid = threadIdx.x;
  if (bid < 16)        d_lstm<1>(whh_f, whh_b, gates, ws+OFF_LC, ws+OFF_STATE, bid, tid, sm);
  else if (bid < 144)  d_spec(qkvB, ws, bid-16, tid, sm);
  else if (bid < 272)  d_mha<1>(qkvA, ws+OFF_ROWSUM, ws+OFF_COLW, bid-144, tid, sm);
  else                 d_conv(qkvB, ws, accum, bid-272, tid, sm, true);
}

// T3: kv_raw(0,B)(64) | gemm(1->A)(768) | coeffs(8)
__global__ __launch_bounds__(256,2) void k_t3(const __bf16* __restrict__ qr, float* __restrict__ ws, int s,
                                              const __bf16* __restrict__ xb, const __bf16* __restrict__ Wg,
                                              __bf16* __restrict__ qw,
                                              const float* __restrict__ mow, const float* __restrict__ mob,
                                              const float* __restrict__ ca_w1, const float* __restrict__ ca_b1,
                                              const float* __restrict__ ca_w2, const float* __restrict__ ca_b2){
  __shared__ __align__(16) char sm[57344];
  int bid = blockIdx.x, tid = threadIdx.x;
  if (bid < 64)        d_polar_kv_raw(qr, ws, s, bid, tid, sm);
  else if (bid < 832)  d_gemm(xb, Wg, nullptr, qw, 12, 1536, 512, bid-64, 768, tid, sm);
  else                 d_coeffs(ws, mow, mob, ca_w1, ca_b1, ca_w2, ca_b2, bid-832, tid, sm);
}

// M_B: polar_ap(s, qr)(512) | spec(qs2)(128)
__global__ __launch_bounds__(256,2) void k_mB(const __bf16* __restrict__ qr, float* __restrict__ ws,
                                              float* __restrict__ accum, int s,
                                              __bf16* __restrict__ qs2){
  __shared__ __align__(16) char sm[80896];
  int bid = blockIdx.x, tid = threadIdx.x;
  if (bid < 512) d_polar_ap(qr, ws, accum, s, bid, tid, sm);
  else           d_spec(qs2, ws, bid-512, tid, sm);
}

// M_C: conv-add(qc)(256) | kv_raw(s, qc)(64) | gemm(W -> qw)(768)
__global__ __launch_bounds__(256,2) void k_mC(const __bf16* __restrict__ qc, float* __restrict__ ws,
                                              float* __restrict__ accum, int s,
                                              const __bf16* __restrict__ xb, const __bf16* __restrict__ Wg,
                                              __bf16* __restrict__ qw){
  __shared__ __align__(16) char sm[70784];
  int bid = blockIdx.x, tid = threadIdx.x;
  if (bid < 256)      d_conv(qc, ws, accum, bid, tid, sm, false);
  else if (bid < 320) d_polar_kv_raw(qc, ws, s, bid-256, tid, sm);
  else                d_gemm(xb, Wg, nullptr, qw, 12, 1536, 512, bid-320, 768, tid, sm);
}

// M_E: conv-add(qc)(256) | kv_raw(s, qc)(64)
__global__ __launch_bounds__(256,2) void k_mE(const __bf16* __restrict__ qc, float* __restrict__ ws,
                                              float* __restrict__ accum, int s){
  __shared__ __align__(16) char sm[70784];
  int bid = blockIdx.x, tid = threadIdx.x;
  if (bid < 256) d_conv(qc, ws, accum, bid, tid, sm, false);
  else           d_polar_kv_raw(qc, ws, s, bid-256, tid, sm);
}

// M_F: polar_ap alone (512)
__global__ __launch_bounds__(256,2) void k_mF(const __bf16* __restrict__ qr, float* __restrict__ ws,
                                              float* __restrict__ accum, int s){
  __shared__ __align__(16) char sm[57600];
  d_polar_ap(qr, ws, accum, s, blockIdx.x, threadIdx.x, sm);
}

__global__ __launch_bounds__(256,1) void k_mha2_w(const __bf16* __restrict__ qkv, float* __restrict__ rowsum,
                                                  float* __restrict__ colw){
  __shared__ __align__(16) char sm[104448];
  d_mha<2>(qkv, rowsum, colw, blockIdx.x, threadIdx.x, sm);
}

__global__ void k_mha3(const __bf16* __restrict__ qkv, const float* __restrict__ colw, float* __restrict__ acmp){
  int h2 = blockIdx.x, b = blockIdx.y, ms = blockIdx.z;  // 4,8,8
  int tid = threadIdx.x;
  __shared__ float cwred[128];
  if (tid < 128){
    float cw=0.f;
    #pragma unroll
    for (int t16=0;t16<16;++t16) cw += colw[(((size_t)t16*8 + b)*4 + h2)*1024 + ms*128 + tid];
    cwred[tid]=cw;
  }
  __syncthreads();
  int e = tid & 127, half = tid >> 7;
  float s = 0.f;
  for (int ml = half*64; ml < half*64+64; ++ml)
    s += cwred[ml] * (float)qkv[((size_t)(b*1024 + ms*128 + ml))*1536 + 1024 + h2*128 + e];
  __shared__ float red[256];
  red[tid]=s; __syncthreads();
  if (tid<128) acmp[((size_t)(ms*8+b))*512 + h2*128 + e] = red[tid]+red[tid+128];
}

// ---------------- output GEMM fused with finalize ----------------
__global__ __launch_bounds__(256,2) void k_gemm_acc(const float* __restrict__ accum, const __bf16* __restrict__ W,
                                                    const float* __restrict__ bias, float* __restrict__ C){
  const int N = 512, K = 512, NB_N = 4;
  __shared__ __bf16 As[128][40];
  __shared__ __bf16 Ws[128][40];
  int tid = threadIdx.x;
  int nwg = gridDim.x, o = blockIdx.x;
  int cpx = nwg >> 3;
  int wg = (o & 7)*cpx + (o >> 3);
  int n0 = (wg % NB_N) * 128, m0 = (wg / NB_N) * 128;
  int l = tid & 63, wid = tid >> 6, lr = l & 15, lg = l >> 4;
  int wr = wid >> 1, wc = wid & 1;
  f32x4 acc[4][4];
  #pragma unroll
  for (int i=0;i<4;++i){ acc[i][0]=fz4(); acc[i][1]=fz4(); acc[i][2]=fz4(); acc[i][3]=fz4(); }
  int srow = tid >> 1, sk = (tid & 1) * 16;
  int row = m0 + srow;
  int bb = row >> 10, nn = row & 1023;
  const float* Abase = accum + ((size_t)bb*8192 + nn)*64;
  const __bf16* Wp = W + (size_t)(n0 + srow) * K + sk;
  const float s3 = 1.0f/3.0f;
  for (int k0 = 0; k0 < K; k0 += 32){
    int c0 = k0 + sk;
    const float* Ap = Abase + (size_t)(c0>>6)*65536 + (c0&63);
    f32x4 a0=*(const f32x4*)(Ap), a1=*(const f32x4*)(Ap+4), a2=*(const f32x4*)(Ap+8), a3=*(const f32x4*)(Ap+12);
    bf16x8 w0 = *(const bf16x8*)(Wp), w1 = *(const bf16x8*)(Wp+8);
    Wp += 32;
    __syncthreads();
    bf16x8 va, vb;
    #pragma unroll
    for (int j=0;j<4;++j){ va[j]=(__bf16)(a0[j]*s3); va[j+4]=(__bf16)(a1[j]*s3);
                           vb[j]=(__bf16)(a2[j]*s3); vb[j+4]=(__bf16)(a3[j]*s3); }
    *(bf16x8*)&As[srow][sk]   = va;  *(bf16x8*)&As[srow][sk+8] = vb;
    *(bf16x8*)&Ws[srow][sk]   = w0;  *(bf16x8*)&Ws[srow][sk+8] = w1;
    __syncthreads();
    bf16x8 aF[4], bF[4];
    #pragma unroll
    for (int mf=0;mf<4;++mf) aF[mf] = *(const bf16x8*)&As[wr*64+mf*16+lr][lg*8];
    #pragma unroll
    for (int nf=0;nf<4;++nf) bF[nf] = *(const bf16x8*)&Ws[wc*64+nf*16+lr][lg*8];
    #pragma unroll
    for (int mf=0;mf<4;++mf)
      #pragma unroll
      for (int nf=0;nf<4;++nf) acc[mf][nf] = MFMA(aF[mf], bF[nf], acc[mf][nf]);
  }
  #pragma unroll
  for (int mf=0;mf<4;++mf)
    #pragma unroll
    for (int nf=0;nf<4;++nf){
      int orow = m0 + wr*64 + mf*16 + lg*4;
      int col = n0 + wc*64 + nf*16 + lr;
      float bv = bias[col];
      #pragma unroll
      for (int r=0;r<4;++r) C[(size_t)(orow+r)*N + col] = acc[mf][nf][r] + bv;
    }
}

// ---------------- launch ----------------
extern "C" void kernel_launch(void* const* d_in, const int* in_sizes, int n_in,
                              void* d_out, int out_size, void* d_ws, size_t ws_size,
                              hipStream_t stream){
  const float* x        = (const float*)d_in[0];
  const float* qkv_w    = (const float*)d_in[3];
  const float* proj_w   = (const float*)d_in[4];
  const float* proj_b   = (const float*)d_in[5];
  const float* pos_sw   = (const float*)d_in[6];
  const float* neg_sw   = (const float*)d_in[7];
  const float* ca_w1    = (const float*)d_in[9];
  const float* ca_b1    = (const float*)d_in[10];
  const float* ca_w2    = (const float*)d_in[11];
  const float* ca_b2    = (const float*)d_in[12];
  const float* wih_f    = (const float*)d_in[13];
  const float* whh_f    = (const float*)d_in[14];
  const float* bih_f    = (const float*)d_in[15];
  const float* bhh_f    = (const float*)d_in[16];
  const float* wih_b    = (const float*)d_in[17];
  const float* whh_b    = (const float*)d_in[18];
  const float* bih_b    = (const float*)d_in[19];
  const float* bhh_b    = (const float*)d_in[20];
  const float* mha_in_w = (const float*)d_in[21];
  const float* mha_in_b = (const float*)d_in[22];
  const float* mha_out_w= (const float*)d_in[23];
  const float* mha_out_b= (const float*)d_in[24];
  const float* ge_b1    = (const float*)d_in[26];
  const float* ge_w2    = (const float*)d_in[27];
  const float* ge_b2    = (const float*)d_in[28];
  const float* spw      = (const float*)d_in[29];
  const float* w5 = (const float*)d_in[30]; const float* b5 = (const float*)d_in[31];
  const float* w7 = (const float*)d_in[32]; const float* b7 = (const float*)d_in[33];
  const float* w9 = (const float*)d_in[34]; const float* b9 = (const float*)d_in[35];
  const float* mode_w = (const float*)d_in[36];
  float* ws  = (float*)d_ws;
  float* out = (float*)d_out;
  __bf16* xb     = (__bf16*)(ws + OFF_XB);
  __bf16* qwb    = (__bf16*)(ws + OFF_QW);
  __bf16* mwb    = (__bf16*)(ws + OFF_MW2);
  __bf16* wfb    = (__bf16*)(ws + OFF_WFB);
  __bf16* pwb    = (__bf16*)(ws + OFF_PWB);
  __bf16* qkvA   = (__bf16*)(ws + OFF_R0);
  __bf16* qkvB   = qkvA + 12582912;
  __bf16* gatesb = (__bf16*)out;               // gates bf16 in d_out (dead before final GEMM)

  k_const<<<1,256,0,stream>>>(ge_b1, ge_w2, ge_b2, mode_w, w5,b5,w7,b7,w9,b9,
                              pos_sw, neg_sw, spw, bih_f,bhh_f,bih_b,bhh_b, ws);
  k_cvt_a<<<2304,256,0,stream>>>(x, wih_f, wih_b, ws);
  // MEGA0: gates GEMM | cvt remainder
  k_mega0<<<2176,256,0,stream>>>(xb, wfb, ws+OFF_LBIAS, gatesb, qkv_w, mha_in_w, proj_w, ws);
  // MEGA1: scan_p1 | mha GEMM->A | qkv0 GEMM->B | xmean
  k_mega1<<<1680,256,0,stream>>>(whh_f, whh_b, gatesb, ws, x, xb, mwb, qwb, mha_in_b, qkvA, qkvB);
  // MEGA2: scan_p2 | spec0(B) | mha<1>(A) | conv0-init(B)
  k_mega2<<<528,256,0,stream>>>(whh_f, whh_b, gatesb, ws, qkvA, qkvB, ws+OFF_ACCUM);
  // MHA finish (A)
  k_mha2_w<<<128,256,0,stream>>>(qkvA, ws+OFF_ROWSUM, ws+OFF_COLW);
  k_mha3<<<dim3(4,8,8),256,0,stream>>>(qkvA, ws+OFF_COLW, ws+OFF_ACMP);
  // T3: kv_raw(0,B) | gemm(1->A) | coeffs
  k_t3<<<840,256,0,stream>>>(qkvB, ws, 0, xb, qwb + 786432, qkvA,
                             mha_out_w, mha_out_b, ca_w1, ca_b1, ca_w2, ca_b2);
  // pipeline
  k_mB<<<640,256,0,stream>>>(qkvB, ws, ws+OFF_ACCUM, 0, qkvA);                     // ap(0,B) | spec(1,A)
  k_mC<<<1088,256,0,stream>>>(qkvA, ws, ws+OFF_ACCUM, 1, xb, qwb + 2*786432, qkvB);// conv(1,A) | kv(1,A) | gemm(2->B)
  k_mB<<<640,256,0,stream>>>(qkvA, ws, ws+OFF_ACCUM, 1, qkvB);                     // ap(1,A) | spec(2,B)
  k_mE<<<320,256,0,stream>>>(qkvB, ws, ws+OFF_ACCUM, 2);                           // conv(2,B) | kv(2,B)
  k_mF<<<512,256,0,stream>>>(qkvB, ws, ws+OFF_ACCUM, 2);                           // ap(2,B)
  k_gemm_acc<<<256,256,0,stream>>>(ws+OFF_ACCUM, pwb, proj_b, out);
}

// Round 19
// 1279.017 us; speedup vs baseline: 1.0200x; 1.0200x over previous
//
#include <hip/hip_runtime.h>
#include <hip/hip_bf16.h>
#include <math.h>

typedef __bf16 bf16x8 __attribute__((ext_vector_type(8)));
typedef __bf16 bf16x4 __attribute__((ext_vector_type(4)));
typedef float  f32x4  __attribute__((ext_vector_type(4)));

#define MFMA(a,b,c) __builtin_amdgcn_mfma_f32_16x16x32_bf16(a, b, c, 0, 0, 0)
#define LOG2E 1.4426950408889634f

// ---------------- workspace float offsets ----------------
static constexpr size_t OFF_R0    = 0;                       // TWO bf16 qkv buffers (A, B)
static constexpr size_t OFF_GXT   = 12582912;
static constexpr size_t OFF_ACCUM = OFF_GXT;                 // 4,194,304
static constexpr size_t OFF_FINAL = OFF_GXT + 4194304;       // bf16 operand area
static constexpr size_t SOFF      = OFF_GXT + 8388608;
static constexpr size_t OFF_ROWSUM= SOFF;                    // 32768 (mha rowsum; later acmp)
static constexpr size_t OFF_ACMP  = OFF_ROWSUM;
static constexpr size_t OFF_COLW  = OFF_ROWSUM + 32768;      // 524288 (mha colw); later BM
static constexpr size_t OFF_BM    = OFF_COLW;
static constexpr size_t OFF_ACM   = OFF_COLW + 524288;
static constexpr size_t OFF_XMEAN = OFF_ACM + 4096;
static constexpr size_t OFF_LC    = OFF_XMEAN + 4096;        // 2048
static constexpr size_t OFF_COEF  = OFF_LC + 2048;           // 256
static constexpr size_t OFF_GMIX  = OFF_COEF + 256;          // 16
static constexpr size_t OFF_MW    = OFF_GMIX + 16;           // 4
static constexpr size_t OFF_CONV9 = OFF_MW + 4;              // 5184
static constexpr size_t OFF_CBIAS = OFF_CONV9 + 5184;        // 64
static constexpr size_t OFF_WEFF  = OFF_CBIAS + 64;          // 4096
static constexpr size_t OFF_PPOW  = OFF_WEFF + 4096;         // 1536
static constexpr size_t OFF_LBIAS = OFF_PPOW + 1536;         // 1024
static constexpr size_t OFF_W2    = OFF_LBIAS + 1024;        // 2048
static constexpr size_t OFF_W1CS  = OFF_W2 + 2048;           // 16384 fl = bf16[32][1024]
static constexpr size_t OFF_W1T   = OFF_W1CS + 16384;        // 16384 fl = bf16[1024][32]
static constexpr size_t OFF_HB    = OFF_W1T + 16384;
static constexpr size_t OFF_STATE = OFF_HB;                  // 12288
static constexpr size_t OFF_XP2   = OFF_HB + 16384;          // 65536 [8][16][512]
// bf16 operand area (inside OFF_FINAL)
static constexpr size_t OFF_XB    = OFF_FINAL;
static constexpr size_t OFF_QW    = OFF_FINAL + 2097152;
static constexpr size_t OFF_MW2   = OFF_FINAL + 3276800;
static constexpr size_t OFF_WFB   = OFF_FINAL + 3670016;
static constexpr size_t OFF_WBB   = OFF_FINAL + 3801088;
static constexpr size_t OFF_PWB   = OFF_FINAL + 3932160;

__device__ __forceinline__ float sigm(float x){ return __builtin_amdgcn_rcpf(1.0f + exp2f(-LOG2E*x)); }
__device__ __forceinline__ float tanhx(float x){ return 2.0f*__builtin_amdgcn_rcpf(1.0f + exp2f(-2.0f*LOG2E*x)) - 1.0f; }
__device__ __forceinline__ unsigned pk2(float a, float b){
  union { __bf16 h[2]; unsigned u; } z; z.h[0]=(__bf16)a; z.h[1]=(__bf16)b; return z.u;
}
__device__ __forceinline__ unsigned pk2b(__bf16 a, __bf16 b){
  union { __bf16 h[2]; unsigned u; } z; z.h[0]=a; z.h[1]=b; return z.u;
}
__device__ __forceinline__ void powpair(float t, float p, float& pos, float& neg){
  float a = fabsf(t);
  float v = (a > 0.f) ? exp2f(p * __log2f(a)) : 0.f;
  pos = (t > 0.f) ? v : 0.f;
  neg = (t < 0.f) ? v : 0.f;
}
__device__ __forceinline__ f32x4 fz4(){ return (f32x4){0.f,0.f,0.f,0.f}; }

// ---------------- fp32 -> bf16 conversion ----------------
__global__ void k_cvt_all(const float* __restrict__ x, const float* __restrict__ qkv_w,
                          const float* __restrict__ mha_in_w, const float* __restrict__ wih_f,
                          const float* __restrict__ wih_b, const float* __restrict__ proj_w,
                          float* __restrict__ ws){
  int b = blockIdx.x;
  const float* src; __bf16* dst; int base;
  if (b < 2048){      src=x;        dst=(__bf16*)(ws+OFF_XB);  base=b; }
  else if (b < 3200){ src=qkv_w;    dst=(__bf16*)(ws+OFF_QW);  base=b-2048; }
  else if (b < 3584){ src=mha_in_w; dst=(__bf16*)(ws+OFF_MW2); base=b-3200; }
  else if (b < 3712){ src=wih_f;    dst=(__bf16*)(ws+OFF_WFB); base=b-3584; }
  else if (b < 3840){ src=wih_b;    dst=(__bf16*)(ws+OFF_WBB); base=b-3712; }
  else {              src=proj_w;   dst=(__bf16*)(ws+OFF_PWB); base=b-3840; }
  int i = (base*256 + threadIdx.x)*8;
  f32x4 u0 = *(const f32x4*)(src+i), u1 = *(const f32x4*)(src+i+4);
  bf16x8 v;
  #pragma unroll
  for (int j=0;j<4;++j){ v[j]=(__bf16)u0[j]; v[j+4]=(__bf16)u1[j]; }
  *(bf16x8*)(dst+i) = v;
}

// ---------------- constants / tables ----------------
__global__ void k_const(const float* __restrict__ ge_b1, const float* __restrict__ ge_w2,
                        const float* __restrict__ ge_b2, const float* __restrict__ mode_w,
                        const float* __restrict__ w5, const float* __restrict__ b5,
                        const float* __restrict__ w7, const float* __restrict__ b7,
                        const float* __restrict__ w9, const float* __restrict__ b9,
                        const float* __restrict__ pos_sw, const float* __restrict__ neg_sw,
                        const float* __restrict__ spw,
                        const float* __restrict__ bih_f, const float* __restrict__ bhh_f,
                        const float* __restrict__ bih_b, const float* __restrict__ bhh_b,
                        float* __restrict__ ws){
  int tid = threadIdx.x; // 256
  __shared__ float mw[3];
  __shared__ float tgh[256];
  __shared__ float sbuf[16];
  tgh[tid] = tanhf(ge_b1[tid]);
  if (tid == 0){
    float m0=mode_w[0], m1=mode_w[1], m2=mode_w[2];
    float mx = fmaxf(m0, fmaxf(m1,m2));
    float e0=expf(m0-mx), e1=expf(m1-mx), e2=expf(m2-mx);
    float s = e0+e1+e2;
    mw[0]=e0/s; mw[1]=e1/s; mw[2]=e2/s;
    ws[OFF_MW+0]=mw[0]; ws[OFF_MW+1]=mw[1]; ws[OFF_MW+2]=mw[2];
  }
  __syncthreads();
  if (tid < 16){
    float s = ge_b2[tid];
    for (int i=0;i<256;++i) s += ge_w2[tid*256+i]*tgh[i];
    sbuf[tid] = s;
  }
  __syncthreads();
  if (tid < 8){
    float a = sbuf[2*tid], b = sbuf[2*tid+1];
    float m = fmaxf(a,b);
    float ea = expf(a-m), eb = expf(b-m);
    ws[OFF_GMIX+2*tid]   = ea/(ea+eb);
    ws[OFF_GMIX+2*tid+1] = eb/(ea+eb);
  }
  for (int j=tid;j<512;j+=256){
    ws[OFF_LBIAS+j]     = bih_f[j]+bhh_f[j];
    ws[OFF_LBIAS+512+j] = bih_b[j]+bhh_b[j];
  }
  for (int f=tid; f<5184; f+=256){
    int d=f/81, t=f%81, ky=t/9, kx=t%9, dy=ky-4, dx=kx-4;
    float v = mw[2]*w9[d*81+t];
    if (dy>=-3 && dy<=3 && dx>=-3 && dx<=3) v += mw[1]*w7[d*49 + (dy+3)*7 + (dx+3)];
    if (dy>=-2 && dy<=2 && dx>=-2 && dx<=2) v += mw[0]*w5[d*25 + (dy+2)*5 + (dx+2)];
    ws[OFF_CONV9+f] = v;
  }
  if (tid<64) ws[OFF_CBIAS+tid] = mw[0]*b5[tid]+mw[1]*b7[tid]+mw[2]*b9[tid];
  for (int f=tid; f<2048; f+=256){
    int h=f>>8, k1=(f>>4)&15, k2=f&15;
    int src = ((h*16+k1)*64 + k2)*2;
    ws[OFF_WEFF+2*f]   = pos_sw[src]   + 0.0625f*neg_sw[src];
    ws[OFF_WEFF+2*f+1] = pos_sw[src+1] + 0.0625f*neg_sw[src+1];
  }
  for (int f=tid; f<1536; f+=256) ws[OFF_PPOW+f] = 1.0f + fabsf(spw[f]);
  for (int f=tid; f<1024; f+=256){
    int e=f>>4, k2=f&15; int ph=(e*k2)&63;
    float th = (float)ph * (6.283185307179586f/64.0f);
    ws[OFF_W2+2*f]   = cosf(th);
    ws[OFF_W2+2*f+1] = -sinf(th);
  }
  __bf16* w1cs = (__bf16*)(ws + OFF_W1CS);
  for (int f=tid; f<32768; f+=256){
    int r=f>>10, m=f&1023; int k1=r&15; int ph=(k1*m)&1023;
    float th = (float)ph * (6.283185307179586f/1024.0f);
    w1cs[f] = (__bf16)((r<16)?cosf(th):-sinf(th));
  }
  __bf16* w1t = (__bf16*)(ws + OFF_W1T);
  for (int f=tid; f<32768; f+=256){
    int n=f>>5, r=f&31; int k1=r&15; int ph=(k1*n)&1023;
    float th = (float)ph * (6.283185307179586f/1024.0f);
    w1t[f] = (__bf16)((r<16)?cosf(th):sinf(th));
  }
}

// ================= device component bodies =================

__device__ __forceinline__ void d_gemm(const __bf16* __restrict__ A, const __bf16* __restrict__ W,
                                       const float* __restrict__ bias, __bf16* __restrict__ C,
                                       int NB_N, int N, int K, int o, int nwg, int tid, char* smraw){
  __bf16 (*As)[40] = (__bf16(*)[40])smraw;
  __bf16 (*Ws)[40] = (__bf16(*)[40])(smraw + 10240);
  int cpx = nwg >> 3;
  int wg = (o & 7)*cpx + (o >> 3);
  int n0 = (wg % NB_N) * 128, m0 = (wg / NB_N) * 128;
  int l = tid & 63, wid = tid >> 6, lr = l & 15, lg = l >> 4;
  int wr = wid >> 1, wc = wid & 1;
  f32x4 acc[4][4];
  #pragma unroll
  for (int i=0;i<4;++i){ acc[i][0]=fz4(); acc[i][1]=fz4(); acc[i][2]=fz4(); acc[i][3]=fz4(); }
  int srow = tid >> 1, sk = (tid & 1) * 16;
  const __bf16* Ap = A + (size_t)(m0 + srow) * K + sk;
  const __bf16* Wp = W + (size_t)(n0 + srow) * K + sk;
  for (int k0 = 0; k0 < K; k0 += 32){
    bf16x8 a0 = *(const bf16x8*)(Ap), a1 = *(const bf16x8*)(Ap+8);
    bf16x8 w0 = *(const bf16x8*)(Wp), w1 = *(const bf16x8*)(Wp+8);
    Ap += 32; Wp += 32;
    __syncthreads();
    *(bf16x8*)&As[srow][sk]   = a0;  *(bf16x8*)&As[srow][sk+8] = a1;
    *(bf16x8*)&Ws[srow][sk]   = w0;  *(bf16x8*)&Ws[srow][sk+8] = w1;
    __syncthreads();
    bf16x8 aF[4], bF[4];
    #pragma unroll
    for (int mf=0;mf<4;++mf) aF[mf] = *(const bf16x8*)&As[wr*64+mf*16+lr][lg*8];
    #pragma unroll
    for (int nf=0;nf<4;++nf) bF[nf] = *(const bf16x8*)&Ws[wc*64+nf*16+lr][lg*8];
    #pragma unroll
    for (int mf=0;mf<4;++mf)
      #pragma unroll
      for (int nf=0;nf<4;++nf) acc[mf][nf] = MFMA(aF[mf], bF[nf], acc[mf][nf]);
  }
  #pragma unroll
  for (int mf=0;mf<4;++mf)
    #pragma unroll
    for (int nf=0;nf<4;++nf){
      int row = m0 + wr*64 + mf*16 + lg*4;
      int col = n0 + wc*64 + nf*16 + lr;
      float bv = bias ? bias[col] : 0.f;
      #pragma unroll
      for (int r=0;r<4;++r) C[(size_t)(row+r)*N + col] = (__bf16)(acc[mf][nf][r] + bv);
    }
}

// ---- LSTM scan half (512 steps). gates bf16 [b][t][1024]. ----
template<int PHASE>
__device__ __forceinline__ void d_lstm(const float* __restrict__ whh_f, const float* __restrict__ whh_b,
                                       const __bf16* __restrict__ gates, float* __restrict__ lc,
                                       float* __restrict__ state, int bid, int tid, char* smraw){
  __builtin_amdgcn_s_setprio(1);
  int dir = bid >> 3, b = bid & 7;
  const float* __restrict__ whh = dir ? whh_b : whh_f;
  const __bf16* gx = gates + (size_t)b*1048576;
  int w=tid>>6, l=tid&63, lr=l&15, lg=l>>4;
  bf16x8 wf[4][2][4];
  #pragma unroll
  for (int q=0;q<4;++q)
    #pragma unroll
    for (int t=0;t<2;++t)
      #pragma unroll
      for (int kc=0;kc<4;++kc){
        const float* p = whh + (size_t)(q*128 + w*32 + t*16 + lr)*128 + kc*32 + lg*8;
        bf16x8 v;
        #pragma unroll
        for (int j=0;j<8;++j) v[j]=(__bf16)p[j];
        wf[q][t][kc]=v;
      }
  __bf16 (*hbuf)[132] = (__bf16(*)[132])smraw;
  int tsel = l&1, rsel = (l>>1)&3;
  int hrow = w*32 + tsel*16 + lg*4 + rsel;
  float* st = state + bid*768 + tid*3;
  float cs, hs;
  if (PHASE==0){
    for (int i=tid; i<264; i+=256) ((__bf16*)hbuf)[i] = (__bf16)0.0f;
    cs=0.f; hs=0.f;
  } else {
    cs = st[0]; hs = st[1];
    hbuf[0][hrow] = (__bf16)st[2];
  }
  long t0 = (PHASE==0) ? (dir?1023:0) : (dir?511:512);
  long tstride = dir ? -1024 : 1024;
  long toff = t0*1024 + dir*512 + hrow;
  float g0[4], g1[4], g2[4], g3[4];
  #pragma unroll
  for (int q=0;q<4;++q) g0[q] = (float)gx[toff + q*128];
  toff += tstride;
  #pragma unroll
  for (int q=0;q<4;++q) g1[q] = (float)gx[toff + q*128];
  toff += tstride;
  #pragma unroll
  for (int q=0;q<4;++q) g2[q] = (float)gx[toff + q*128];
  toff += tstride;
  #pragma unroll
  for (int q=0;q<4;++q) g3[q] = (float)gx[toff + q*128];
  toff += tstride;
  __syncthreads();

#define LSTM_STEP(RB, WB, G) { \
    float gq[4]; \
    _Pragma("unroll") for (int q=0;q<4;++q) gq[q]=G[q]; \
    _Pragma("unroll") for (int q=0;q<4;++q) G[q] = (float)gx[toff + q*128]; \
    toff += tstride; \
    if (toff < 0) toff = 0; \
    if (toff > 1048000) toff = 1048000; \
    bf16x8 hf[4]; \
    _Pragma("unroll") for (int kc=0;kc<4;++kc) hf[kc] = *(const bf16x8*)&hbuf[RB][kc*32 + lg*8]; \
    f32x4 acc[4][2]; \
    _Pragma("unroll") for (int q=0;q<4;++q){ acc[q][0]=fz4(); acc[q][1]=fz4(); } \
    _Pragma("unroll") for (int kc=0;kc<4;++kc) \
      _Pragma("unroll") for (int q=0;q<4;++q){ \
        acc[q][0] = MFMA(wf[q][0][kc], hf[kc], acc[q][0]); \
        acc[q][1] = MFMA(wf[q][1][kc], hf[kc], acc[q][1]); } \
    float gv[4]; \
    _Pragma("unroll") for (int q=0;q<4;++q){ \
      f32x4 v0 = acc[q][0], v1 = acc[q][1]; \
      float a01 = (rsel&1) ? v0[1] : v0[0]; \
      float a23 = (rsel&1) ? v0[3] : v0[2]; \
      float av  = (rsel&2) ? a23 : a01; \
      float b01 = (rsel&1) ? v1[1] : v1[0]; \
      float b23 = (rsel&1) ? v1[3] : v1[2]; \
      float bv  = (rsel&2) ? b23 : b01; \
      gv[q] = (tsel ? bv : av) + gq[q]; } \
    float ii=sigm(gv[0]), ff=sigm(gv[1]), gg=tanhx(gv[2]), oo=sigm(gv[3]); \
    cs = ff*cs + ii*gg; \
    float hv = oo*tanhx(cs); \
    hs += hv; \
    if (!(l&8)) hbuf[WB][hrow] = (__bf16)hv; \
    asm volatile("s_waitcnt lgkmcnt(0)" ::: "memory"); \
    __builtin_amdgcn_sched_barrier(0); \
    __builtin_amdgcn_s_barrier(); \
    __builtin_amdgcn_sched_barrier(0); }

  for (int it=0; it<128; ++it){
    LSTM_STEP(0, 1, g0)
    LSTM_STEP(1, 0, g1)
    LSTM_STEP(0, 1, g2)
    LSTM_STEP(1, 0, g3)
  }
#undef LSTM_STEP
  if (PHASE==0){
    st[0]=cs; st[1]=hs; st[2]=(float)hbuf[0][hrow];
  } else {
    if (!(l&8)) lc[b*256 + dir*128 + hrow] = hs*(1.f/1024.f);
  }
  __builtin_amdgcn_s_setprio(0);
}

__device__ __forceinline__ void d_xmean(const float* __restrict__ x, float* __restrict__ xpart,
                                        int f, int tid){
  int sl = f & 15, b = f >> 4;
  #pragma unroll
  for (int cc=0; cc<2; ++cc){
    int c = tid + cc*256;
    float s=0.f;
    for (int n=sl*64; n<sl*64+64; ++n) s += x[((size_t)(b*1024+n))*512 + c];
    xpart[((size_t)(b*16+sl))*512 + c] = s;
  }
}

// ---- MHA sweep (MODE 1: rowsum, MODE 2: colw) ----
template<int MODE>
__device__ __forceinline__ void d_mha(const __bf16* __restrict__ qkv, float* __restrict__ rowsum,
                                      float* __restrict__ colw, int f, int tid, char* smraw){
  int rb = f & 3, h2 = (f>>2) & 3, b = f >> 4;
  __bf16 (*Qs)[136] = (__bf16(*)[136])smraw;
  __bf16 (*Ks)[136] = (__bf16(*)[136])(smraw + 69632);
  int l=tid&63, w=tid>>6, lr=l&15, lg=l>>4;
  {
    const float qs = LOG2E / sqrtf(128.0f);
    int row = tid;
    const __bf16* p = qkv + ((size_t)(b*1024 + rb*256 + row))*1536 + h2*128;
    #pragma unroll
    for (int cc=0; cc<128; cc+=8){
      bf16x8 u = *(const bf16x8*)(p+cc);
      bf16x8 v;
      #pragma unroll
      for (int j=0;j<8;++j) v[j]=(__bf16)((float)u[j]*qs);
      *(bf16x8*)&Qs[row][cc] = v;
    }
  }
  float rs[4][4];
  if (MODE==1){
    #pragma unroll
    for (int mf=0;mf<4;++mf){ rs[mf][0]=0.f; rs[mf][1]=0.f; rs[mf][2]=0.f; rs[mf][3]=0.f; }
  } else {
    #pragma unroll
    for (int mf=0;mf<4;++mf)
      #pragma unroll
      for (int r=0;r<4;++r)
        rs[mf][r] = 1.0f / rowsum[((size_t)(b*4+h2))*1024 + rb*256 + w*64 + mf*16 + lg*4 + r];
  }
  for (int mc=0; mc<8; ++mc){
    __syncthreads();
    {
      int row = tid>>1, co = (tid&1)*64;
      const __bf16* p = qkv + ((size_t)(b*1024 + mc*128 + row))*1536 + 512 + h2*128 + co;
      #pragma unroll
      for (int cc=0; cc<64; cc+=8)
        *(bf16x8*)&Ks[row][co+cc] = *(const bf16x8*)(p+cc);
    }
    __syncthreads();
    f32x4 acc[4][8];
    #pragma unroll
    for (int mf=0;mf<4;++mf)
      #pragma unroll
      for (int nf=0;nf<8;++nf) acc[mf][nf]=fz4();
    #pragma unroll
    for (int ks=0;ks<4;++ks){
      bf16x8 aF[4], bFv[8];
      #pragma unroll
      for (int mf=0;mf<4;++mf) aF[mf] = *(const bf16x8*)&Qs[w*64+mf*16+lr][ks*32+lg*8];
      #pragma unroll
      for (int nf=0;nf<8;++nf) bFv[nf] = *(const bf16x8*)&Ks[nf*16+lr][ks*32+lg*8];
      #pragma unroll
      for (int mf=0;mf<4;++mf)
        #pragma unroll
        for (int nf=0;nf<8;++nf) acc[mf][nf] = MFMA(aF[mf], bFv[nf], acc[mf][nf]);
    }
    if (MODE==1){
      #pragma unroll
      for (int mf=0;mf<4;++mf)
        #pragma unroll
        for (int nf=0;nf<8;++nf)
          #pragma unroll
          for (int r=0;r<4;++r) rs[mf][r] += exp2f(acc[mf][nf][r]);
    } else {
      #pragma unroll
      for (int nf=0;nf<8;++nf){
        float cv = 0.f;
        #pragma unroll
        for (int mf=0;mf<4;++mf)
          #pragma unroll
          for (int r=0;r<4;++r) cv += exp2f(acc[mf][nf][r])*rs[mf][r];
        cv += __shfl_xor(cv,16);
        cv += __shfl_xor(cv,32);
        if (lg==0)
          colw[(((size_t)(rb*4+w)*8 + b)*4 + h2)*1024 + mc*128 + nf*16 + lr] = cv;
      }
    }
  }
  if (MODE==1){
    #pragma unroll
    for (int mf=0;mf<4;++mf)
      #pragma unroll
      for (int r=0;r<4;++r){
        float v = rs[mf][r];
        v += __shfl_xor(v,1); v += __shfl_xor(v,2); v += __shfl_xor(v,4); v += __shfl_xor(v,8);
        if (lr==0) rowsum[((size_t)(b*4+h2))*1024 + rb*256 + w*64 + mf*16 + lg*4 + r] = v;
      }
  }
}

// ---- spectral fused (in-place q/k) ----
__device__ __forceinline__ void d_spec(__bf16* __restrict__ qkv, const float* __restrict__ ws,
                                       int f, int tid, char* smraw){
  int qk = f & 1, h = (f>>1) & 7, b = f >> 4;
  int colbase = qk*512 + h*64;
  int l=tid&63, w=tid>>6, lr=l&15, lg=l>>4;
  __bf16 (*tT)[520] = (__bf16(*)[520])smraw;                 // 66560 B
  float (*M1)[64]   = (float(*)[64])(smraw + 66560);          // 8192 B
  float (*G2)[2]    = (float(*)[2])(smraw + 66560 + 8192);    // 2048 B
  __bf16* hbl       = (__bf16*)(smraw + 66560 + 8192 + 2048); // 4096 B
  const __bf16* w1cs = (const __bf16*)(ws + OFF_W1CS);
  f32x4 acc1[2]; acc1[0]=fz4(); acc1[1]=fz4();
  for (int c0=0; c0<2; ++c0){
    __syncthreads();
    {
      int p = tid;
      int m0 = c0*512 + 2*p;
      const __bf16* r0 = qkv + ((size_t)(b*1024 + m0))*1536 + colbase;
      const __bf16* r1 = r0 + 1536;
      #pragma unroll
      for (int e=0;e<64;e+=8){
        bf16x8 u0 = *(const bf16x8*)(r0+e);
        bf16x8 u1 = *(const bf16x8*)(r1+e);
        #pragma unroll
        for (int j=0;j<8;++j) *(unsigned*)&tT[e+j][2*p] = pk2b(u0[j], u1[j]);
      }
    }
    __syncthreads();
    for (int ks=0; ks<16; ++ks){
      bf16x8 bfv = *(const bf16x8*)&tT[w*16+lr][ks*32+lg*8];
      #pragma unroll
      for (int mf=0;mf<2;++mf){
        bf16x8 af = *(const bf16x8*)(w1cs + (size_t)(mf*16+lr)*1024 + c0*512 + ks*32 + lg*8);
        acc1[mf] = MFMA(af, bfv, acc1[mf]);
      }
    }
  }
  #pragma unroll
  for (int mf=0;mf<2;++mf)
    #pragma unroll
    for (int r=0;r<4;++r) M1[mf*16 + lg*4 + r][w*16 + lr] = acc1[mf][r];
  __syncthreads();
  {
    int k1 = tid>>4, k2 = tid&15;
    float tfr=0.f, tfi=0.f;
    const float* w2 = ws + OFF_W2;
    for (int e=0;e<64;++e){
      float mr = M1[k1][e], mi = M1[16+k1][e];
      float cr = w2[(e*16+k2)*2], ci = w2[(e*16+k2)*2+1];
      tfr += mr*cr - mi*ci;
      tfi += mr*ci + mi*cr;
    }
    float wr = ws[OFF_WEFF + ((size_t)h*256 + k1*16 + k2)*2];
    float wi = ws[OFF_WEFF + ((size_t)h*256 + k1*16 + k2)*2 + 1];
    G2[tid][0] = tfr*wr - tfi*wi;
    G2[tid][1] = tfr*wi + tfi*wr;
  }
  __syncthreads();
  {
    const float* w2 = ws + OFF_W2;
    for (int f2=tid; f2<1024; f2+=256){
      int k1 = f2>>6, d = f2&63;
      float hr=0.f, hi=0.f;
      #pragma unroll
      for (int k2=0;k2<16;++k2){
        float gr=G2[k1*16+k2][0], gi=G2[k1*16+k2][1];
        float sc = k2 ? 2.f : 1.f;
        float cr = sc*w2[(d*16+k2)*2];
        float ci = -sc*w2[(d*16+k2)*2+1];
        hr += gr*cr - gi*ci;
        hi += gr*ci + gi*cr;
      }
      const float inv = 1.0f/65536.0f;
      hbl[d*32 + k1]      = (__bf16)(hr*inv);
      hbl[d*32 + 16 + k1] = (__bf16)(-hi*inv);
    }
  }
  __syncthreads();
  const __bf16* w1t = (const __bf16*)(ws + OFF_W1T);
  bf16x8 bF[4];
  #pragma unroll
  for (int nf=0;nf<4;++nf) bF[nf] = *(const bf16x8*)&hbl[(nf*16+lr)*32 + lg*8];
  for (int pass=0; pass<4; ++pass){
    int rowbase = w*256 + pass*64;
    f32x4 acc[4][4];
    #pragma unroll
    for (int mf=0;mf<4;++mf){ acc[mf][0]=fz4(); acc[mf][1]=fz4(); acc[mf][2]=fz4(); acc[mf][3]=fz4(); }
    #pragma unroll
    for (int mf=0;mf<4;++mf){
      bf16x8 aF = *(const bf16x8*)(w1t + (size_t)(rowbase+mf*16+lr)*32 + lg*8);
      #pragma unroll
      for (int nf=0;nf<4;++nf) acc[mf][nf] = MFMA(aF, bF[nf], acc[mf][nf]);
    }
    #pragma unroll
    for (int mf=0;mf<4;++mf)
      #pragma unroll
      for (int nf=0;nf<4;++nf)
        #pragma unroll
        for (int r=0;r<4;++r){
          int n = rowbase + mf*16 + lg*4 + r;
          int d = nf*16 + lr;
          qkv[((size_t)(b*1024+n))*1536 + colbase + d] = (__bf16)acc[mf][nf][r];
        }
  }
}

// ---- conv (init: write, else add) ----
__device__ __forceinline__ void d_conv(const __bf16* __restrict__ qkv, const float* __restrict__ ws,
                                       float* __restrict__ accum, int f, int tid, char* smraw, bool init){
  int sl = f & 3, h = (f>>2)&7, b = f>>5;
  float (*vs)[16] = (float(*)[16])smraw;                 // 65536 B
  float (*wc)[81] = (float(*)[81])(smraw + 65536);       // 5184 B
  float* cb       = (float*)(smraw + 65536 + 5184);      // 64 B
  #pragma unroll
  for (int it=0; it<8; ++it){
    int flat = tid + 256*it;
    int pix = flat>>1, cg = (flat&1)*8;
    bf16x8 u = *(const bf16x8*)(qkv + ((size_t)(b*1024+pix))*1536 + 1024 + h*64 + sl*16 + cg);
    #pragma unroll
    for (int j=0;j<8;++j) vs[pix][cg+j] = (float)u[j];
  }
  for (int f2=tid; f2<16*81; f2+=256) wc[f2/81][f2%81] = ws[OFF_CONV9 + (size_t)(sl*16 + f2/81)*81 + (f2%81)];
  if (tid<16) cb[tid] = ws[OFF_CBIAS + sl*16 + tid];
  __syncthreads();
  #pragma unroll
  for (int cc=0; cc<2; ++cc){
    int col = tid + 256*cc;
    int c = col & 15, x = col >> 4;
    float a[32];
    #pragma unroll
    for (int y=0;y<32;++y) a[y]=0.f;
    #pragma unroll
    for (int dx=-4; dx<=4; ++dx){
      int xx = x+dx;
      bool xv = (xx>=0)&&(xx<32);
      float colv[40];
      #pragma unroll
      for (int i=0;i<40;++i){
        int yy = i-4;
        colv[i] = (xv && yy>=0 && yy<32) ? vs[yy*32+xx][c] : 0.f;
      }
      #pragma unroll
      for (int dy=0; dy<9; ++dy){
        float wv = wc[c][dy*9 + dx+4];
        #pragma unroll
        for (int y=0;y<32;++y) a[y] += wv*colv[y+dy];
      }
    }
    float bias = cb[c];
    #pragma unroll
    for (int y=0;y<32;++y){
      size_t oi = ((size_t)((b*8+h)*1024) + y*32 + x)*64 + sl*16 + c;
      if (init) accum[oi] = a[y] + bias;
      else      accum[oi] += a[y] + bias;
    }
  }
}

// ---- polarity KV reduction -> Bm (f = h + 8*b) ----
__device__ __forceinline__ void d_polar_kv(const __bf16* __restrict__ qkv, float* __restrict__ ws,
                                           int s, int f, int tid, char* smraw){
  int h = f & 7, b = f >> 3;
  int l=tid&63, w=tid>>6, lr=l&15, lg=l>>4;
  float* plds = (float*)smraw;
  __bf16* kpT = (__bf16*)smraw;
  __bf16* knT = (__bf16*)(smraw + 17408);
  __bf16* vT  = (__bf16*)(smraw + 34816);
  float* scal = (float*)(smraw + 56576);
  float* pvs  = scal + 8;
  if (tid<4)  scal[tid] = ws[OFF_COEF + b*32 + h*4 + tid];
  if (tid==4) scal[4] = ws[OFF_GMIX + 2*h];
  if (tid==5) scal[5] = ws[OFF_GMIX + 2*h+1];
  if (tid<64) pvs[tid] = ws[OFF_PPOW + ((size_t)s*8+h)*64 + tid];
  for (int i=tid; i<16*136; i+=256) vT[64*136 + i] = (__bf16)((i<136)?1.0f:0.0f);
  f32x4 acc[4][5];
  #pragma unroll
  for (int mf=0;mf<4;++mf)
    #pragma unroll
    for (int nf=0;nf<5;++nf) acc[mf][nf]=fz4();
  for (int mc=0;mc<8;++mc){
    __syncthreads();
    #pragma unroll
    for (int it=0; it<16; ++it){
      int flat = tid + 256*it;
      int d = flat & 63, np = flat >> 6;
      int n = mc*128 + 2*np;
      const __bf16* kr = qkv + ((size_t)(b*1024+n))*1536 + 512 + h*64 + d;
      const __bf16* vr = qkv + ((size_t)(b*1024+n))*1536 + 1024 + h*64 + d;
      float p = pvs[d];
      float k0=(float)kr[0], k1=(float)kr[1536];
      float kp0,kn0,kp1,kn1;
      powpair(k0,p,kp0,kn0); powpair(k1,p,kp1,kn1);
      *(unsigned*)&kpT[d*136 + 2*np] = pk2(kp0,kp1);
      *(unsigned*)&knT[d*136 + 2*np] = pk2(kn0,kn1);
      *(unsigned*)&vT [d*136 + 2*np] = pk2b(vr[0], vr[1536]);
    }
    __syncthreads();
    const __bf16* A = (w&2)?knT:kpT;
    int kh = (w&1)*64;
    #pragma unroll
    for (int ks=0;ks<2;++ks){
      bf16x8 aF[4];
      #pragma unroll
      for (int mf=0;mf<4;++mf) aF[mf] = *(const bf16x8*)&A[(mf*16+lr)*136 + kh + ks*32 + lg*8];
      #pragma unroll
      for (int nf=0;nf<5;++nf){
        bf16x8 bFv = *(const bf16x8*)&vT[(nf*16+lr)*136 + kh + ks*32 + lg*8];
        #pragma unroll
        for (int mf=0;mf<4;++mf) acc[mf][nf] = MFMA(aF[mf], bFv, acc[mf][nf]);
      }
    }
  }
  __syncthreads();
  float* kvf = plds;
  if ((w&1)==0){
    int mat = w>>1;
    #pragma unroll
    for (int mf=0;mf<4;++mf)
      #pragma unroll
      for (int nf=0;nf<5;++nf)
        #pragma unroll
        for (int r=0;r<4;++r)
          kvf[((size_t)mat*64 + mf*16+lg*4+r)*80 + nf*16+lr] = acc[mf][nf][r];
  }
  __syncthreads();
  if (w&1){
    int mat = w>>1;
    #pragma unroll
    for (int mf=0;mf<4;++mf)
      #pragma unroll
      for (int nf=0;nf<5;++nf)
        #pragma unroll
        for (int r=0;r<4;++r)
          kvf[((size_t)mat*64 + mf*16+lg*4+r)*80 + nf*16+lr] += acc[mf][nf][r];
  }
  __syncthreads();
  __bf16* bmg = (__bf16*)(ws + OFF_BM) + (size_t)(b*8+h)*10240;
  {
    float c0=scal[0], c1=scal[1], c2=scal[2], c3=scal[3], g0=scal[4], g1=scal[5];
    for (int f2=tid; f2<80*128; f2+=256){
      int e=f2>>7, kk=f2&127;
      float v;
      if (e<64){
        if (kk<64) v = g0*c0*kvf[kk*80+e] + g1*c2*kvf[(64+kk)*80+e];
        else { int k2=kk-64; v = g0*c1*kvf[(64+k2)*80+e] + g1*c3*kvf[k2*80+e]; }
      } else if (e==64){
        v = (kk<64) ? kvf[kk*80+64] : kvf[(64+(kk-64))*80+64];
      } else v = 0.f;
      bmg[f2] = (__bf16)v;
    }
  }
}

// ---- polarity apply (f = pass8 + 8*(h + 8*b); always += accum) ----
__device__ __forceinline__ void d_polar_ap(const __bf16* __restrict__ qkv, const float* __restrict__ ws,
                                           float* __restrict__ accum, int s, int f, int tid, char* smraw){
  int pass8 = f & 7, h = (f>>3)&7, b = f>>6;
  int l=tid&63, w=tid>>6, lr=l&15, lg=l>>4;
  __bf16* At  = (__bf16*)smraw;                 // 34816 B
  __bf16* BmL = (__bf16*)(smraw + 34816);       // 21760 B
  float* zb   = (float*)(smraw + 56576);        // 512 B
  float* pvs  = (float*)(smraw + 57088);        // 256 B
  if (tid<64) pvs[tid] = ws[OFF_PPOW + ((size_t)s*8+h)*64 + tid];
  {
    const __bf16* bmg = (const __bf16*)(ws + OFF_BM) + (size_t)(b*8+h)*10240;
    for (int u=tid; u<80*16; u+=256){
      int e=u>>4, kx=(u&15)*8;
      *(bf16x8*)&BmL[e*136+kx] = *(const bf16x8*)(bmg + e*128 + kx);
    }
  }
  __syncthreads();
  #pragma unroll
  for (int it=0; it<8; ++it){
    int flat = tid + 256*it;
    int row = flat>>4, dg = flat&15;
    int n = pass8*128 + row;
    const __bf16* qr = qkv + ((size_t)(b*1024+n))*1536 + h*64 + dg*4;
    bf16x4 u = *(const bf16x4*)qr;
    float qp[4], qn[4];
    #pragma unroll
    for (int j=0;j<4;++j) powpair((float)u[j], pvs[dg*4+j], qp[j], qn[j]);
    *(unsigned*)&At[(row*136) + dg*4]        = pk2(qp[0],qp[1]);
    *(unsigned*)&At[(row*136) + dg*4+2]      = pk2(qp[2],qp[3]);
    *(unsigned*)&At[(row*136) + 64 + dg*4]   = pk2(qn[0],qn[1]);
    *(unsigned*)&At[(row*136) + 64 + dg*4+2] = pk2(qn[2],qn[3]);
  }
  __syncthreads();
  f32x4 a2[2][5];
  #pragma unroll
  for (int mf=0;mf<2;++mf)
    #pragma unroll
    for (int nf=0;nf<5;++nf) a2[mf][nf]=fz4();
  #pragma unroll
  for (int ks=0;ks<4;++ks){
    bf16x8 aF[2];
    #pragma unroll
    for (int mf=0;mf<2;++mf) aF[mf] = *(const bf16x8*)&At[(w*32+mf*16+lr)*136 + ks*32 + lg*8];
    #pragma unroll
    for (int nf=0;nf<5;++nf){
      bf16x8 bFv = *(const bf16x8*)&BmL[(nf*16+lr)*136 + ks*32 + lg*8];
      #pragma unroll
      for (int mf=0;mf<2;++mf) a2[mf][nf] = MFMA(aF[mf], bFv, a2[mf][nf]);
    }
  }
  if (lr==0){
    #pragma unroll
    for (int mf=0;mf<2;++mf)
      #pragma unroll
      for (int r=0;r<4;++r) zb[w*32 + mf*16 + lg*4 + r] = a2[mf][4][r] + 1e-6f;
  }
  __syncthreads();
  #pragma unroll
  for (int mf=0;mf<2;++mf){
    float rz[4];
    #pragma unroll
    for (int r=0;r<4;++r) rz[r] = 1.0f / zb[w*32 + mf*16 + lg*4 + r];
    #pragma unroll
    for (int nf=0;nf<4;++nf)
      #pragma unroll
      for (int r=0;r<4;++r){
        int n = pass8*128 + w*32 + mf*16 + lg*4 + r;
        int e = nf*16 + lr;
        size_t oi = ((size_t)((b*8+h)*1024) + n)*64 + e;
        accum[oi] += a2[mf][nf][r]*rz[r];
      }
  }
}

// ================= kernels =================

__global__ __launch_bounds__(256,2) void k_gemm_bf(const __bf16* __restrict__ A, const __bf16* __restrict__ W,
                                                   const float* __restrict__ bias, __bf16* __restrict__ C,
                                                   int NB_N, int N, int K){
  __shared__ __align__(16) char sm[20480];
  d_gemm(A, W, bias, C, NB_N, N, K, blockIdx.x, gridDim.x, threadIdx.x, sm);
}

// MEGA1: scan_p1(16) | mha GEMM->A(768) | qkv0 GEMM->B(768) | xmean(128)
__global__ __launch_bounds__(256,1) void k_mega1(const float* __restrict__ whh_f, const float* __restrict__ whh_b,
                                                 const __bf16* __restrict__ gates, float* __restrict__ ws,
                                                 const float* __restrict__ x,
                                                 const __bf16* __restrict__ xb, const __bf16* __restrict__ mwb,
                                                 const __bf16* __restrict__ qwb,
                                                 const float* __restrict__ mha_in_b,
                                                 __bf16* __restrict__ qkvA, __bf16* __restrict__ qkvB){
  __shared__ __align__(16) char sm[20480];
  int bid = blockIdx.x, tid = threadIdx.x;
  if (bid < 16)         d_lstm<0>(whh_f, whh_b, gates, ws+OFF_LC, ws+OFF_STATE, bid, tid, sm);
  else if (bid < 784)   d_gemm(xb, mwb, mha_in_b, qkvA, 12, 1536, 512, bid-16, 768, tid, sm);
  else if (bid < 1552)  d_gemm(xb, qwb, nullptr,   qkvB, 12, 1536, 512, bid-784, 768, tid, sm);
  else                  d_xmean(x, ws+OFF_XP2, bid-1552, tid);
}

// MEGA2: scan_p2(16) | spec0(128) | mha<1>(128) | conv0-init(256)
__global__ __launch_bounds__(256,1) void k_mega2(const float* __restrict__ whh_f, const float* __restrict__ whh_b,
                                                 const __bf16* __restrict__ gates, float* __restrict__ ws,
                                                 const __bf16* __restrict__ qkvA, __bf16* __restrict__ qkvB,
                                                 float* __restrict__ accum){
  __shared__ __align__(16) char sm[104448];
  int bid = blockIdx.x, tid = threadIdx.x;
  if (bid < 16)        d_lstm<1>(whh_f, whh_b, gates, ws+OFF_LC, ws+OFF_STATE, bid, tid, sm);
  else if (bid < 144)  d_spec(qkvB, ws, bid-16, tid, sm);
  else if (bid < 272)  d_mha<1>(qkvA, ws+OFF_ROWSUM, ws+OFF_COLW, bid-144, tid, sm);
  else                 d_conv(qkvB, ws, accum, bid-272, tid, sm, true);
}

// M_A: polar_kv(s, qr)(64) | gemm(W -> qw)(768)
__global__ __launch_bounds__(256,2) void k_mA(const __bf16* __restrict__ qr, float* __restrict__ ws, int s,
                                              const __bf16* __restrict__ xb, const __bf16* __restrict__ Wg,
                                              __bf16* __restrict__ qw){
  __shared__ __align__(16) char sm[57344];
  int bid = blockIdx.x, tid = threadIdx.x;
  if (bid < 64) d_polar_kv(qr, ws, s, bid, tid, sm);
  else          d_gemm(xb, Wg, nullptr, qw, 12, 1536, 512, bid-64, 768, tid, sm);
}

// M_B: polar_ap(s, qr)(512) | spec(qs2)(128)
__global__ __launch_bounds__(256,2) void k_mB(const __bf16* __restrict__ qr, float* __restrict__ ws,
                                              float* __restrict__ accum, int s,
                                              __bf16* __restrict__ qs2){
  __shared__ __align__(16) char sm[80896];
  int bid = blockIdx.x, tid = threadIdx.x;
  if (bid < 512) d_polar_ap(qr, ws, accum, s, bid, tid, sm);
  else           d_spec(qs2, ws, bid-512, tid, sm);
}

// M_C: conv-add(qc)(256) | polar_kv(s, qc)(64) | gemm(W -> qw)(768)
__global__ __launch_bounds__(256,2) void k_mC(const __bf16* __restrict__ qc, float* __restrict__ ws,
                                              float* __restrict__ accum, int s,
                                              const __bf16* __restrict__ xb, const __bf16* __restrict__ Wg,
                                              __bf16* __restrict__ qw){
  __shared__ __align__(16) char sm[70784];
  int bid = blockIdx.x, tid = threadIdx.x;
  if (bid < 256)      d_conv(qc, ws, accum, bid, tid, sm, false);
  else if (bid < 320) d_polar_kv(qc, ws, s, bid-256, tid, sm);
  else                d_gemm(xb, Wg, nullptr, qw, 12, 1536, 512, bid-320, 768, tid, sm);
}

// M_E: conv-add(qc)(256) | polar_kv(s, qc)(64)
__global__ __launch_bounds__(256,2) void k_mE(const __bf16* __restrict__ qc, float* __restrict__ ws,
                                              float* __restrict__ accum, int s){
  __shared__ __align__(16) char sm[70784];
  int bid = blockIdx.x, tid = threadIdx.x;
  if (bid < 256) d_conv(qc, ws, accum, bid, tid, sm, false);
  else           d_polar_kv(qc, ws, s, bid-256, tid, sm);
}

// M_F: polar_ap alone (512)
__global__ __launch_bounds__(256,2) void k_mF(const __bf16* __restrict__ qr, float* __restrict__ ws,
                                              float* __restrict__ accum, int s){
  __shared__ __align__(16) char sm[57600];
  d_polar_ap(qr, ws, accum, s, blockIdx.x, threadIdx.x, sm);
}

__global__ __launch_bounds__(256,1) void k_mha2_w(const __bf16* __restrict__ qkv, float* __restrict__ rowsum,
                                                  float* __restrict__ colw){
  __shared__ __align__(16) char sm[104448];
  d_mha<2>(qkv, rowsum, colw, blockIdx.x, threadIdx.x, sm);
}

__global__ void k_mha3(const __bf16* __restrict__ qkv, const float* __restrict__ colw, float* __restrict__ acmp){
  int h2 = blockIdx.x, b = blockIdx.y, ms = blockIdx.z;  // 4,8,8
  int tid = threadIdx.x;
  __shared__ float cwred[128];
  if (tid < 128){
    float cw=0.f;
    #pragma unroll
    for (int t16=0;t16<16;++t16) cw += colw[(((size_t)t16*8 + b)*4 + h2)*1024 + ms*128 + tid];
    cwred[tid]=cw;
  }
  __syncthreads();
  int e = tid & 127, half = tid >> 7;
  float s = 0.f;
  for (int ml = half*64; ml < half*64+64; ++ml)
    s += cwred[ml] * (float)qkv[((size_t)(b*1024 + ms*128 + ml))*1536 + 1024 + h2*128 + e];
  __shared__ float red[256];
  red[tid]=s; __syncthreads();
  if (tid<128) acmp[((size_t)(ms*8+b))*512 + h2*128 + e] = red[tid]+red[tid+128];
}

__global__ __launch_bounds__(256) void k_coeffs(float* __restrict__ ws,
                        const float* __restrict__ mow, const float* __restrict__ mob,
                        const float* __restrict__ ca_w1, const float* __restrict__ ca_b1,
                        const float* __restrict__ ca_w2, const float* __restrict__ ca_b2){
  int b = blockIdx.x, tid = threadIdx.x;
  __shared__ float av[512], comb[512], hid[256];
  for (int i=tid;i<512;i+=256){
    float s = 0.f;
    #pragma unroll
    for (int ms=0; ms<8; ++ms) s += ws[OFF_ACMP + ((size_t)(ms*8+b))*512 + i];
    av[i] = s*(1.f/1024.f);
  }
  __syncthreads();
  for (int c=tid;c<512;c+=256){
    float s = mob[c];
    for (int k=0;k<512;++k) s += mow[(size_t)c*512+k]*av[k];
    float xm = 0.f;
    #pragma unroll
    for (int sl=0; sl<16; ++sl) xm += ws[OFF_XP2 + ((size_t)(b*16+sl))*512 + c];
    comb[c] = s + xm*(1.f/1024.f) + ((c<256) ? ws[OFF_LC + b*256 + c] : 0.f);
  }
  __syncthreads();
  for (int j=tid;j<256;j+=256){
    float s = ca_b1[j];
    for (int k=0;k<512;++k) s += ca_w1[(size_t)j*512+k]*comb[k];
    hid[j] = fmaxf(s,0.f);
  }
  __syncthreads();
  if (tid<32){
    float s = ca_b2[tid];
    for (int k=0;k<256;++k) s += ca_w2[tid*256+k]*hid[k];
    ws[OFF_COEF + b*32 + tid] = 1.f/(1.f+expf(-s));
  }
}

// ---------------- output GEMM fused with finalize ----------------
__global__ __launch_bounds__(256,2) void k_gemm_acc(const float* __restrict__ accum, const __bf16* __restrict__ W,
                                                    const float* __restrict__ bias, float* __restrict__ C){
  const int N = 512, K = 512, NB_N = 4;
  __shared__ __bf16 As[128][40];
  __shared__ __bf16 Ws[128][40];
  int tid = threadIdx.x;
  int nwg = gridDim.x, o = blockIdx.x;
  int cpx = nwg >> 3;
  int wg = (o & 7)*cpx + (o >> 3);
  int n0 = (wg % NB_N) * 128, m0 = (wg / NB_N) * 128;
  int l = tid & 63, wid = tid >> 6, lr = l & 15, lg = l >> 4;
  int wr = wid >> 1, wc = wid & 1;
  f32x4 acc[4][4];
  #pragma unroll
  for (int i=0;i<4;++i){ acc[i][0]=fz4(); acc[i][1]=fz4(); acc[i][2]=fz4(); acc[i][3]=fz4(); }
  int srow = tid >> 1, sk = (tid & 1) * 16;
  int row = m0 + srow;
  int bb = row >> 10, nn = row & 1023;
  const float* Abase = accum + ((size_t)bb*8192 + nn)*64;
  const __bf16* Wp = W + (size_t)(n0 + srow) * K + sk;
  const float s3 = 1.0f/3.0f;
  for (int k0 = 0; k0 < K; k0 += 32){
    int c0 = k0 + sk;
    const float* Ap = Abase + (size_t)(c0>>6)*65536 + (c0&63);
    f32x4 a0=*(const f32x4*)(Ap), a1=*(const f32x4*)(Ap+4), a2=*(const f32x4*)(Ap+8), a3=*(const f32x4*)(Ap+12);
    bf16x8 w0 = *(const bf16x8*)(Wp), w1 = *(const bf16x8*)(Wp+8);
    Wp += 32;
    __syncthreads();
    bf16x8 va, vb;
    #pragma unroll
    for (int j=0;j<4;++j){ va[j]=(__bf16)(a0[j]*s3); va[j+4]=(__bf16)(a1[j]*s3);
                           vb[j]=(__bf16)(a2[j]*s3); vb[j+4]=(__bf16)(a3[j]*s3); }
    *(bf16x8*)&As[srow][sk]   = va;  *(bf16x8*)&As[srow][sk+8] = vb;
    *(bf16x8*)&Ws[srow][sk]   = w0;  *(bf16x8*)&Ws[srow][sk+8] = w1;
    __syncthreads();
    bf16x8 aF[4], bF[4];
    #pragma unroll
    for (int mf=0;mf<4;++mf) aF[mf] = *(const bf16x8*)&As[wr*64+mf*16+lr][lg*8];
    #pragma unroll
    for (int nf=0;nf<4;++nf) bF[nf] = *(const bf16x8*)&Ws[wc*64+nf*16+lr][lg*8];
    #pragma unroll
    for (int mf=0;mf<4;++mf)
      #pragma unroll
      for (int nf=0;nf<4;++nf) acc[mf][nf] = MFMA(aF[mf], bF[nf], acc[mf][nf]);
  }
  #pragma unroll
  for (int mf=0;mf<4;++mf)
    #pragma unroll
    for (int nf=0;nf<4;++nf){
      int orow = m0 + wr*64 + mf*16 + lg*4;
      int col = n0 + wc*64 + nf*16 + lr;
      float bv = bias[col];
      #pragma unroll
      for (int r=0;r<4;++r) C[(size_t)(orow+r)*N + col] = acc[mf][nf][r] + bv;
    }
}

// ---------------- launch ----------------
extern "C" void kernel_launch(void* const* d_in, const int* in_sizes, int n_in,
                              void* d_out, int out_size, void* d_ws, size_t ws_size,
                              hipStream_t stream){
  const float* x        = (const float*)d_in[0];
  const float* qkv_w    = (const float*)d_in[3];
  const float* proj_w   = (const float*)d_in[4];
  const float* proj_b   = (const float*)d_in[5];
  const float* pos_sw   = (const float*)d_in[6];
  const float* neg_sw   = (const float*)d_in[7];
  const float* ca_w1    = (const float*)d_in[9];
  const float* ca_b1    = (const float*)d_in[10];
  const float* ca_w2    = (const float*)d_in[11];
  const float* ca_b2    = (const float*)d_in[12];
  const float* wih_f    = (const float*)d_in[13];
  const float* whh_f    = (const float*)d_in[14];
  const float* bih_f    = (const float*)d_in[15];
  const float* bhh_f    = (const float*)d_in[16];
  const float* wih_b    = (const float*)d_in[17];
  const float* whh_b    = (const float*)d_in[18];
  const float* bih_b    = (const float*)d_in[19];
  const float* bhh_b    = (const float*)d_in[20];
  const float* mha_in_w = (const float*)d_in[21];
  const float* mha_in_b = (const float*)d_in[22];
  const float* mha_out_w= (const float*)d_in[23];
  const float* mha_out_b= (const float*)d_in[24];
  const float* ge_b1    = (const float*)d_in[26];
  const float* ge_w2    = (const float*)d_in[27];
  const float* ge_b2    = (const float*)d_in[28];
  const float* spw      = (const float*)d_in[29];
  const float* w5 = (const float*)d_in[30]; const float* b5 = (const float*)d_in[31];
  const float* w7 = (const float*)d_in[32]; const float* b7 = (const float*)d_in[33];
  const float* w9 = (const float*)d_in[34]; const float* b9 = (const float*)d_in[35];
  const float* mode_w = (const float*)d_in[36];
  float* ws  = (float*)d_ws;
  float* out = (float*)d_out;
  __bf16* xb     = (__bf16*)(ws + OFF_XB);
  __bf16* qwb    = (__bf16*)(ws + OFF_QW);
  __bf16* mwb    = (__bf16*)(ws + OFF_MW2);
  __bf16* wfb    = (__bf16*)(ws + OFF_WFB);
  __bf16* pwb    = (__bf16*)(ws + OFF_PWB);
  __bf16* qkvA   = (__bf16*)(ws + OFF_R0);
  __bf16* qkvB   = qkvA + 12582912;
  __bf16* gatesb = (__bf16*)out;               // gates bf16 in d_out (dead before final GEMM)

  k_const<<<1,256,0,stream>>>(ge_b1, ge_w2, ge_b2, mode_w, w5,b5,w7,b7,w9,b9,
                              pos_sw, neg_sw, spw, bih_f,bhh_f,bih_b,bhh_b, ws);
  k_cvt_all<<<3968,256,0,stream>>>(x, qkv_w, mha_in_w, wih_f, wih_b, proj_w, ws);
  k_gemm_bf<<<512,256,0,stream>>>(xb, wfb, ws+OFF_LBIAS, gatesb, 8, 1024, 512);
  // MEGA1: scan_p1 | mha GEMM->A | qkv0 GEMM->B | xmean
  k_mega1<<<1680,256,0,stream>>>(whh_f, whh_b, gatesb, ws, x, xb, mwb, qwb, mha_in_b, qkvA, qkvB);
  // MEGA2: scan_p2 | spec0(B) | mha<1>(A) | conv0-init(B)
  k_mega2<<<528,256,0,stream>>>(whh_f, whh_b, gatesb, ws, qkvA, qkvB, ws+OFF_ACCUM);
  // MHA finish (A), then coeffs
  k_mha2_w<<<128,256,0,stream>>>(qkvA, ws+OFF_ROWSUM, ws+OFF_COLW);
  k_mha3<<<dim3(4,8,8),256,0,stream>>>(qkvA, ws+OFF_COLW, ws+OFF_ACMP);
  k_coeffs<<<8,256,0,stream>>>(ws, mha_out_w, mha_out_b, ca_w1, ca_b1, ca_w2, ca_b2);
  // pipelined scales with alternating buffers (A free after mha3)
  k_mA<<<832,256,0,stream>>>(qkvB, ws, 0, xb, qwb + 786432, qkvA);                 // kv(0,B) | gemm(1->A)
  k_mB<<<640,256,0,stream>>>(qkvB, ws, ws+OFF_ACCUM, 0, qkvA);                     // ap(0,B) | spec(1,A)
  k_mC<<<1088,256,0,stream>>>(qkvA, ws, ws+OFF_ACCUM, 1, xb, qwb + 2*786432, qkvB);// conv(1,A) | kv(1,A) | gemm(2->B)
  k_mB<<<640,256,0,stream>>>(qkvA, ws, ws+OFF_ACCUM, 1, qkvB);                     // ap(1,A) | spec(2,B)
  k_mE<<<320,256,0,stream>>>(qkvB, ws, ws+OFF_ACCUM, 2);                           // conv(2,B) | kv(2,B)
  k_mF<<<512,256,0,stream>>>(qkvB, ws, ws+OFF_ACCUM, 2);                           // ap(2,B)
  k_gemm_acc<<<256,256,0,stream>>>(ws+OFF_ACCUM, pwb, proj_b, out);
}